// Round 3
// baseline (1694.508 us; speedup 1.0000x reference)
//
#include <hip/hip_runtime.h>
#include <cstdint>
#include <cstddef>

// ---------------------------------------------------------------------------
// CapsNet forward, f32 end-to-end (precision-critical: the sort-based squash
// flips discrete segments on ~1e-7 perturbations of s_j, so no bf16 on that
// path).
//
// Workspace layout (floats). u_hat overlaps the dead w_t/x1/pu regions.
// Total = 34,873,088 floats = 133.0 MiB.
// ---------------------------------------------------------------------------

#define BATCH 100

static const size_t OFF_WT   = 0;            // 256*81*256 = 5,308,416   (dead after prim)
static const size_t OFF_X1   = 5308416;      // 100*256*576 = 14,745,600 (dead after prim)
static const size_t OFF_PU   = 20054016;     // 4*100*2048*8 = 6,553,600 (prim partials; dead after k_ured)
static const size_t OFF_UHAT = 0;            // 100*2048*160 = 32,768,000 (built after prim)
static const size_t OFF_U    = 32768000;     // 100*2048*8 = 1,638,400 (u, then u_sq in place)
static const size_t OFF_BIJ  = 34406400;     // 2048*10
static const size_t OFF_CIJ  = 34426880;     // 2048*10
static const size_t OFF_SP   = 34447360;     // 100*16*160 s_j partials
static const size_t OFF_VJ   = 34703360;     // 100*160
static const size_t OFF_IDX  = 34719360;     // 100 ints (128 slots)
static const size_t OFF_H1   = 34719488;     // 100*512
static const size_t OFF_H2   = 34770688;     // 100*1024  -> end 34,873,088

// piecewise-affine squash constants
#define PT1f -13.46416092f
#define PA1f 0.000242759f
#define PB1f 0.024488359f
#define PA2f 0.002769205f
#define PB2f 0.06089699f
#define PT3f 13.23405266f
#define PA3f -0.002828244f
#define PB3f 0.061313814f
#define PA4f -0.000219038f
#define PB4f 0.023874787f

#define DT1f -0.075410217f
#define DA1f -0.074520095f
#define DB1f 0.349297946f
#define DA2f -0.534473989f
#define DB2f 0.27196494f
#define DT3f 0.062207676f
#define DA3f 0.637642944f
#define DB3f 0.295330779f
#define DA4f 0.169344703f
#define DB4f 0.353784456f

// ---------------------------------------------------------------------------
// w_t[(ci*81+tap)*256 + co]  <-  prim_w[co][ci][tap]
// ---------------------------------------------------------------------------
__global__ __launch_bounds__(256)
void k_transpose_w(const float* __restrict__ w, float* __restrict__ wt) {
  __shared__ float tile[64 * 82];
  int ci = blockIdx.x, co0 = blockIdx.y * 64, t = threadIdx.x;
  for (int f = t; f < 64 * 81; f += 256) {
    int col = f / 81, tap = f - col * 81;
    tile[col * 82 + tap] = w[(size_t)(co0 + col) * 20736 + (size_t)ci * 81 + tap];
  }
  __syncthreads();
  for (int g = t; g < 64 * 81; g += 256) {
    int tap = g / 64, col = g - tap * 64;
    wt[((size_t)ci * 81 + tap) * 256 + co0 + col] = tile[col * 82 + tap];
  }
}

// ---------------------------------------------------------------------------
// conv1 + bias + relu: data(100,1,32,32) -> x1(100,256,24,24)
// ---------------------------------------------------------------------------
__global__ __launch_bounds__(256)
void k_conv1(const float* __restrict__ data, const float* __restrict__ cw,
             const float* __restrict__ cb, float* __restrict__ x1) {
  __shared__ float img[1024];
  __shared__ float wl[81 * 32];     // [tap][c]
  int b = blockIdx.x, cg = blockIdx.y, t = threadIdx.x;
  for (int f = t; f < 1024; f += 256) img[f] = data[(size_t)b * 1024 + f];
  for (int f = t; f < 2592; f += 256) {
    int tap = f >> 5, c = f & 31;
    wl[f] = cw[(size_t)(cg * 32 + c) * 81 + tap];
  }
  __syncthreads();
  for (int task = t; task < 1152; task += 256) {
    int q = task % 144, cq = task / 144;
    int p0 = q * 4, oh = p0 / 24, ow0 = p0 % 24;
    float a[4][4];
#pragma unroll
    for (int i = 0; i < 4; ++i)
#pragma unroll
      for (int j = 0; j < 4; ++j) a[i][j] = 0.f;
    for (int kh = 0; kh < 9; ++kh) {
      const float* ir = &img[(oh + kh) * 32 + ow0];
      const float* wr = &wl[kh * 9 * 32 + cq * 4];
#pragma unroll
      for (int kw = 0; kw < 9; ++kw) {
        float4 wv = *(const float4*)(wr + kw * 32);
        float wa[4] = {wv.x, wv.y, wv.z, wv.w};
        float xv[4] = {ir[kw], ir[kw + 1], ir[kw + 2], ir[kw + 3]};
#pragma unroll
        for (int i = 0; i < 4; ++i)
#pragma unroll
          for (int j = 0; j < 4; ++j) a[i][j] = fmaf(wa[i], xv[j], a[i][j]);
      }
    }
#pragma unroll
    for (int cc = 0; cc < 4; ++cc) {
      int c = cg * 32 + cq * 4 + cc;
      float bias = cb[c];
      float4 o4 = make_float4(fmaxf(a[cc][0] + bias, 0.f), fmaxf(a[cc][1] + bias, 0.f),
                              fmaxf(a[cc][2] + bias, 0.f), fmaxf(a[cc][3] + bias, 0.f));
      *(float4*)&x1[((size_t)(b * 256 + c) * 24 + oh) * 24 + ow0] = o4;
    }
  }
}

// ---------------------------------------------------------------------------
// prim conv v3: x1(100,256,24,24) -> PU[split](100,2048,8), 9x9 stride 2.
// Block = 512 thr = 4 batches x (8 coq x 16 posq); tile 4b x 32co x 64pos,
// 64 ci per block (4-way ci split). One w-tile serves 4 batches.
// x staged PHASE-SPLIT (even/odd cols): every inner LDS read is ds_read_b128.
// LDS 39.2 KB -> 4 blocks/CU x 8 waves = 32 waves/CU (100% cap).
// Grid 800 blocks <= 1024 resident slots -> ALL blocks co-resident, no tail.
// ---------------------------------------------------------------------------
__global__ __launch_bounds__(512, 8)
void k_prim(const float* __restrict__ x1, const float* __restrict__ wt,
            float* __restrict__ pu) {
  __shared__ float wsh[2 * 81 * 32];       // [cil][tap][co32]         20736 B
  __shared__ float xsh[4 * 2 * 2 * 288];   // [tb][cil][phase][24x12]  18432 B
  int t = threadIdx.x;
  int tb = t >> 7, tl = t & 127;
  int coq = tl >> 4, posq = tl & 15;
  int oh = posq >> 1, owq = posq & 1;
  int ci_base = blockIdx.x * 64, cog = blockIdx.y, bq = blockIdx.z;
  int b = bq * 4 + tb;

  float acc[4][4];
#pragma unroll
  for (int i = 0; i < 4; ++i)
#pragma unroll
    for (int j = 0; j < 4; ++j) acc[i][j] = 0.f;

#pragma unroll 1
  for (int ci0 = ci_base; ci0 < ci_base + 64; ci0 += 2) {
    __syncthreads();
    // stage x: 1152 float4 jobs (4 tb x 2 cil x 144), phase-split on write
    for (int f = t; f < 1152; f += 512) {
      int tbj = f / 288, m = f - tbj * 288;
      int cil = m / 144, mm = m - cil * 144;
      int r = mm / 6, mq = mm - r * 6;
      float4 v = *(const float4*)&x1[((size_t)(bq * 4 + tbj) * 256 + ci0 + cil) * 576 +
                                     r * 24 + mq * 4];
      float* eb = &xsh[((tbj * 2 + cil) * 2 + 0) * 288 + r * 12 + mq * 2];
      *(float2*)eb = make_float2(v.x, v.z);          // even cols 4mq, 4mq+2
      *(float2*)(eb + 288) = make_float2(v.y, v.w);  // odd  cols 4mq+1, 4mq+3
    }
    // stage w: 1296 float4 jobs (2 cil x 81 tap x 8 colq)
    for (int f = t; f < 1296; f += 512) {
      int cil = f / 648, rem = f - cil * 648;
      int tap = rem >> 3, cq = rem & 7;
      float4 v = *(const float4*)&wt[((size_t)(ci0 + cil) * 81 + tap) * 256 +
                                     cog * 32 + cq * 4];
      *(float4*)&wsh[(cil * 81 + tap) * 32 + cq * 4] = v;
    }
    __syncthreads();
#pragma unroll
    for (int cil = 0; cil < 2; ++cil) {
      const float* xb0 = &xsh[((tb * 2 + cil) * 2 + 0) * 288 + owq * 4];
      const float* wb0 = &wsh[cil * 81 * 32 + coq * 4];
#pragma unroll 3
      for (int kh = 0; kh < 9; ++kh) {
        int r = 2 * oh + kh;
        const float* xe = xb0 + r * 12;
        float e[8], o8[8];
        *(float4*)&e[0]  = *(const float4*)xe;
        *(float4*)&e[4]  = *(const float4*)(xe + 4);
        *(float4*)&o8[0] = *(const float4*)(xe + 288);
        *(float4*)&o8[4] = *(const float4*)(xe + 292);
        const float* wr = wb0 + kh * 9 * 32;
#pragma unroll
        for (int kp = 0; kp < 5; ++kp) {               // kw = 2*kp (even cols)
          float4 wv = *(const float4*)(wr + kp * 64);
          float wa[4] = {wv.x, wv.y, wv.z, wv.w};
#pragma unroll
          for (int i = 0; i < 4; ++i)
#pragma unroll
            for (int j = 0; j < 4; ++j) acc[i][j] = fmaf(wa[i], e[kp + j], acc[i][j]);
        }
#pragma unroll
        for (int kp = 0; kp < 4; ++kp) {               // kw = 2*kp+1 (odd cols)
          float4 wv = *(const float4*)(wr + 32 + kp * 64);
          float wa[4] = {wv.x, wv.y, wv.z, wv.w};
#pragma unroll
          for (int i = 0; i < 4; ++i)
#pragma unroll
            for (int j = 0; j < 4; ++j) acc[i][j] = fmaf(wa[i], o8[kp + j], acc[i][j]);
        }
      }
    }
  }
  // partial write (no bias; k_ured adds it): pu[split][b][r=co*8+oh][ow]
  float* pp = pu + (((size_t)blockIdx.x * BATCH + b) * 2048 +
                    (cog * 32 + coq * 4) * 8 + oh) * 8 + owq * 4;
#pragma unroll
  for (int cc = 0; cc < 4; ++cc) {
    float4 o4 = make_float4(acc[cc][0], acc[cc][1], acc[cc][2], acc[cc][3]);
    *(float4*)(pp + cc * 64) = o4;   // co+1 -> r+8 -> +64 floats
  }
}

// u = pu0+pu1+pu2+pu3 + bias (sequential order = closest to reference sum)
__global__ __launch_bounds__(256)
void k_ured(const float* __restrict__ pu, const float* __restrict__ pb,
            float* __restrict__ u) {
  int g4 = blockIdx.x * 256 + threadIdx.x;     // 409,600 float4s
  if (g4 >= 409600) return;
  size_t g = (size_t)g4 * 4;
  float4 a = *(const float4*)(pu + g);
  float4 b = *(const float4*)(pu + 1638400 + g);
  float4 c = *(const float4*)(pu + 2 * 1638400 + g);
  float4 d = *(const float4*)(pu + 3 * 1638400 + g);
  int r = (int)((g >> 3) & 2047);
  float bias = pb[r >> 3];
  float4 o;
  o.x = ((a.x + b.x) + c.x) + d.x + bias;
  o.y = ((a.y + b.y) + c.y) + d.y + bias;
  o.z = ((a.z + b.z) + c.z) + d.z + bias;
  o.w = ((a.w + b.w) + c.w) + d.w + bias;
  *(float4*)(u + g) = o;
}

// ---------------------------------------------------------------------------
// primary squash: stable bitonic sort per batch row + exact where-chain,
// then u_sq = mag * u in place.
// ---------------------------------------------------------------------------
__global__ __launch_bounds__(256)
void k_squash(float* __restrict__ u) {
  __shared__ float kv[2048];
  __shared__ int kid[2048];
  __shared__ int red[256];
  int b = blockIdx.x, t = threadIdx.x;
  for (int r = t; r < 2048; r += 256) {
    kv[r] = u[((size_t)b * 2048 + r) * 8];
    kid[r] = r;
  }
  __syncthreads();
  for (int size = 2; size <= 2048; size <<= 1) {
    for (int stride = size >> 1; stride > 0; stride >>= 1) {
#pragma unroll 1
      for (int s = 0; s < 4; ++s) {
        int i = t + s * 256;
        int pos = 2 * i - (i & (stride - 1));
        int q = pos + stride;
        float va = kv[pos], vb = kv[q];
        int ia = kid[pos], ib = kid[q];
        bool gt = (va > vb) || (va == vb && ia > ib);
        bool up = ((pos & size) == 0);
        if (gt == up) { kv[pos] = vb; kv[q] = va; kid[pos] = ib; kid[q] = ia; }
      }
      __syncthreads();
    }
  }
  int loc = 0;
#pragma unroll
  for (int s = 0; s < 8; ++s) loc += (kv[t + s * 256] < PT1f) ? 1 : 0;
  red[t] = loc; __syncthreads();
  for (int off = 128; off; off >>= 1) { if (t < off) red[t] += red[t + off]; __syncthreads(); }
  int i1 = red[0]; __syncthreads();
  float m1v[8];
  loc = 0;
#pragma unroll
  for (int s = 0; s < 8; ++s) {
    int p = t + s * 256;
    float v = kv[p];
    float m = (p < i1 - 1) ? (PA1f * v + PB1f) : v;
    m1v[s] = m;
    loc += (m < 0.f) ? 1 : 0;
  }
  red[t] = loc; __syncthreads();
  for (int off = 128; off; off >>= 1) { if (t < off) red[t] += red[t + off]; __syncthreads(); }
  int i2 = red[0]; __syncthreads();
  float m2v[8];
  loc = 0;
#pragma unroll
  for (int s = 0; s < 8; ++s) {
    int p = t + s * 256;
    float m = (p >= i1 && p < i2 - 1) ? (PA2f * m1v[s] + PB2f) : m1v[s];
    m2v[s] = m;
    loc += (m < PT3f) ? 1 : 0;
  }
  red[t] = loc; __syncthreads();
  for (int off = 128; off; off >>= 1) { if (t < off) red[t] += red[t + off]; __syncthreads(); }
  int i3 = red[0]; __syncthreads();
#pragma unroll
  for (int s = 0; s < 8; ++s) {
    int p = t + s * 256;
    float m = m2v[s];
    m = (p >= i2 && p < i3 - 1) ? (PA3f * m + PB3f) : m;
    m = (p >= i3 && p < 2047) ? (PA4f * m + PB4f) : m;
    int rid = kid[p];
    float* row = u + ((size_t)b * 2048 + rid) * 8;
    float4 lo = *(float4*)row;
    float4 hi = *(float4*)(row + 4);
    lo.x *= m; lo.y *= m; lo.z *= m; lo.w *= m;
    hi.x *= m; hi.y *= m; hi.z *= m; hi.w *= m;
    *(float4*)row = lo;
    *(float4*)(row + 4) = hi;
  }
}

// ---------------------------------------------------------------------------
// u_hat[b][r][c*16+o] = sum_i W_dc[r][c][o][i] * u_sq[b][r][i]
// ---------------------------------------------------------------------------
__global__ __launch_bounds__(192)
void k_uhat(const float* __restrict__ Wdc, const float* __restrict__ usq,
            float* __restrict__ uhat) {
  int t = threadIdx.x;
  if (t >= 160) return;
  int r0 = blockIdx.x * 8;
  for (int rl = 0; rl < 8; ++rl) {
    int r = r0 + rl;
    const float* wp = Wdc + ((size_t)r * 160 + t) * 8;
    float4 wa = *(const float4*)wp;
    float4 wb = *(const float4*)(wp + 4);
#pragma unroll 2
    for (int b = 0; b < BATCH; ++b) {
      const float* us = usq + ((size_t)b * 2048 + r) * 8;
      float v = us[0] * wa.x + us[1] * wa.y + us[2] * wa.z + us[3] * wa.w +
                us[4] * wb.x + us[5] * wb.y + us[6] * wb.z + us[7] * wb.w;
      uhat[((size_t)b * 2048 + r) * 160 + t] = v;
    }
  }
}

__global__ void k_zero(float* __restrict__ p, int n) {
  int i = blockIdx.x * blockDim.x + threadIdx.x;
  if (i < n) p[i] = 0.f;
}

__global__ __launch_bounds__(256)
void k_softc(const float* __restrict__ bij, float* __restrict__ cij) {
  __shared__ float red[256];
  int c = blockIdx.x, t = threadIdx.x;
  float m = -3.402823466e38f;
  for (int r = t; r < 2048; r += 256) m = fmaxf(m, bij[r * 10 + c]);
  red[t] = m; __syncthreads();
  for (int off = 128; off; off >>= 1) { if (t < off) red[t] = fmaxf(red[t], red[t + off]); __syncthreads(); }
  m = red[0]; __syncthreads();
  float s = 0.f;
  for (int r = t; r < 2048; r += 256) s += expf(bij[r * 10 + c] - m);
  red[t] = s; __syncthreads();
  for (int off = 128; off; off >>= 1) { if (t < off) red[t] += red[t + off]; __syncthreads(); }
  s = red[0];
  for (int r = t; r < 2048; r += 256) cij[r * 10 + c] = expf(bij[r * 10 + c] - m) / s;
}

__global__ __launch_bounds__(192)
void k_sjpart(const float* __restrict__ cij, const float* __restrict__ uhat,
              float* __restrict__ sp) {
  __shared__ float cl[1280];
  int b = blockIdx.x, ch = blockIdx.y, t = threadIdx.x;
  for (int f = t; f < 1280; f += 192) cl[f] = cij[(size_t)ch * 1280 + f];
  __syncthreads();
  if (t < 160) {
    int c = t >> 4;
    float acc = 0.f;
    const float* up = uhat + ((size_t)b * 2048 + ch * 128) * 160 + t;
#pragma unroll 4
    for (int rl = 0; rl < 128; ++rl) acc += cl[rl * 10 + c] * up[(size_t)rl * 160];
    sp[((size_t)b * 16 + ch) * 160 + t] = acc;
  }
}

__global__ __launch_bounds__(192)
void k_sjred(const float* __restrict__ sp, float* __restrict__ vj,
             float* __restrict__ dout, int finalit) {
  __shared__ float sl[160];
  __shared__ float fl[10];
  int b = blockIdx.x, t = threadIdx.x;
  if (t < 160) {
    float a = 0.f;
#pragma unroll
    for (int ch = 0; ch < 16; ++ch) a += sp[((size_t)b * 16 + ch) * 160 + t];
    sl[t] = a;
  }
  __syncthreads();
  if (t == 0) {
    float sv[10]; int rk[10];
    for (int c = 0; c < 10; ++c) sv[c] = sl[c * 16];
    for (int c = 0; c < 10; ++c) {
      int r = 0;
      for (int k = 0; k < 10; ++k)
        r += ((sv[k] < sv[c]) || (sv[k] == sv[c] && k < c)) ? 1 : 0;
      rk[c] = r;
    }
    int i1 = 0;
    for (int c = 0; c < 10; ++c) i1 += (sv[c] < DT1f) ? 1 : 0;
    float m1[10];
    for (int c = 0; c < 10; ++c) m1[c] = (rk[c] < i1 - 1) ? (DA1f * sv[c] + DB1f) : sv[c];
    int i2 = 0;
    for (int c = 0; c < 10; ++c) i2 += (m1[c] < 0.f) ? 1 : 0;
    float m2[10];
    for (int c = 0; c < 10; ++c)
      m2[c] = (rk[c] >= i1 && rk[c] < i2 - 1) ? (DA2f * m1[c] + DB2f) : m1[c];
    int i3 = 0;
    for (int c = 0; c < 10; ++c) i3 += (m2[c] < DT3f) ? 1 : 0;
    for (int c = 0; c < 10; ++c) {
      float m = (rk[c] >= i2 && rk[c] < i3 - 1) ? (DA3f * m2[c] + DB3f) : m2[c];
      m = (rk[c] >= i3 && rk[c] < 9) ? (DA4f * m + DB4f) : m;
      fl[c] = m;
    }
  }
  __syncthreads();
  if (t < 160) {
    int c = t >> 4, o = t & 15;
    float fv = fl[c];
    float v = fv * ((o == 0) ? fv : sl[t]);
    vj[(size_t)b * 160 + t] = v;
    if (finalit) dout[(size_t)b * 1184 + t] = v;
  }
}

__global__ __launch_bounds__(192)
void k_amean(const float* __restrict__ uhat, const float* __restrict__ vj,
             float* __restrict__ bij) {
  __shared__ float vl[16000];
  int t = threadIdx.x, r0 = blockIdx.x * 8;
  for (int f = t; f < 16000; f += 192) vl[f] = vj[f];
  __syncthreads();
  if (t < 160) {
    int c = t >> 4;
    for (int rl = 0; rl < 8; ++rl) {
      int r = r0 + rl;
      float acc = 0.f;
      const float* up = uhat + (size_t)r * 160 + t;
#pragma unroll 4
      for (int b = 0; b < BATCH; ++b) acc += up[(size_t)b * 2048 * 160] * vl[b * 160 + t];
      for (int off = 8; off; off >>= 1) acc += __shfl_down(acc, off, 16);
      if ((t & 15) == 0) bij[r * 10 + c] += acc / 100.0f;
    }
  }
}

__global__ __launch_bounds__(256)
void k_cls(const float* __restrict__ vj, int* __restrict__ idxg) {
  __shared__ float cl[1000];
  __shared__ float cm[10];
  __shared__ float cs[10];
  int t = threadIdx.x;
  for (int f = t; f < 1000; f += 256) {
    int b = f / 10, c = f - b * 10;
    float s = 0.f;
#pragma unroll
    for (int o = 0; o < 16; ++o) {
      float v = vj[(size_t)b * 160 + c * 16 + o];
      s += v * v;
    }
    cl[f] = sqrtf(s);
  }
  __syncthreads();
  if (t < 10) {
    float m = -3.402823466e38f;
    for (int b = 0; b < BATCH; ++b) m = fmaxf(m, cl[b * 10 + t]);
    float s = 0.f;
    for (int b = 0; b < BATCH; ++b) s += expf(cl[b * 10 + t] - m);
    cm[t] = m; cs[t] = s;
  }
  __syncthreads();
  for (int b = t; b < BATCH; b += 256) {
    float best = -1.f; int bi = 0;
    for (int c = 0; c < 10; ++c) {
      float val = expf(cl[b * 10 + c] - cm[c]) / cs[c];
      if (val > best) { best = val; bi = c; }
    }
    idxg[b] = bi;
  }
}

__global__ __launch_bounds__(256)
void k_dec1(const float* __restrict__ w1, const float* __restrict__ b1,
            const float* __restrict__ vj, const int* __restrict__ idxg,
            float* __restrict__ h1) {
  int b = blockIdx.x, t = threadIdx.x;
  int id = idxg[b];
  const float* v = vj + (size_t)b * 160 + id * 16;
  for (int j = t; j < 512; j += 256) {
    float acc = b1[j];
    const float* wr = w1 + (size_t)j * 160 + id * 16;
#pragma unroll
    for (int o = 0; o < 16; ++o) acc += wr[o] * v[o];
    h1[(size_t)b * 512 + j] = fmaxf(acc, 0.f);
  }
}

__global__ __launch_bounds__(256)
void k_dec2(const float* __restrict__ w2, const float* __restrict__ b2,
            const float* __restrict__ h1, float* __restrict__ h2) {
  __shared__ float red[4][64][4];
  int t = threadIdx.x, lane = t & 63, strip = t >> 6;
  int j = blockIdx.x * 64 + lane, bs = blockIdx.y * 4;
  float acc[4] = {0.f, 0.f, 0.f, 0.f};
  const float* wr = w2 + (size_t)j * 512 + strip * 128;
  const float* hb = h1 + (size_t)bs * 512 + strip * 128;
  for (int k4 = 0; k4 < 32; ++k4) {
    float4 wv = *(const float4*)(wr + k4 * 4);
    const float* h0 = hb + k4 * 4;
#pragma unroll
    for (int q = 0; q < 4; ++q) {
      float4 hv = *(const float4*)(h0 + q * 512);
      acc[q] += wv.x * hv.x + wv.y * hv.y + wv.z * hv.z + wv.w * hv.w;
    }
  }
#pragma unroll
  for (int q = 0; q < 4; ++q) red[strip][lane][q] = acc[q];
  __syncthreads();
  if (strip == 0) {
    float bias = b2[j];
#pragma unroll
    for (int q = 0; q < 4; ++q) {
      float tot = red[0][lane][q] + red[1][lane][q] + red[2][lane][q] + red[3][lane][q] + bias;
      h2[(size_t)(bs + q) * 1024 + j] = fmaxf(tot, 0.f);
    }
  }
}

__global__ __launch_bounds__(256)
void k_dec3(const float* __restrict__ w3, const float* __restrict__ b3,
            const float* __restrict__ h2, float* __restrict__ dout) {
  __shared__ float red[4][64][4];
  int t = threadIdx.x, lane = t & 63, strip = t >> 6;
  int j = blockIdx.x * 64 + lane, bs = blockIdx.y * 4;
  float acc[4] = {0.f, 0.f, 0.f, 0.f};
  const float* wr = w3 + (size_t)j * 1024 + strip * 256;
  const float* hb = h2 + (size_t)bs * 1024 + strip * 256;
  for (int k4 = 0; k4 < 64; ++k4) {
    float4 wv = *(const float4*)(wr + k4 * 4);
    const float* h0 = hb + k4 * 4;
#pragma unroll
    for (int q = 0; q < 4; ++q) {
      float4 hv = *(const float4*)(h0 + q * 1024);
      acc[q] += wv.x * hv.x + wv.y * hv.y + wv.z * hv.z + wv.w * hv.w;
    }
  }
#pragma unroll
  for (int q = 0; q < 4; ++q) red[strip][lane][q] = acc[q];
  __syncthreads();
  if (strip == 0) {
    float bias = b3[j];
#pragma unroll
    for (int q = 0; q < 4; ++q) {
      float tot = red[0][lane][q] + red[1][lane][q] + red[2][lane][q] + red[3][lane][q] + bias;
      dout[(size_t)(bs + q) * 1184 + 160 + j] = 1.f / (1.f + expf(-tot));
    }
  }
}

// ---------------------------------------------------------------------------
extern "C" void kernel_launch(void* const* d_in, const int* in_sizes, int n_in,
                              void* d_out, int out_size, void* d_ws, size_t ws_size,
                              hipStream_t stream) {
  (void)in_sizes; (void)n_in; (void)out_size; (void)ws_size;
  const float* data = (const float*)d_in[0];
  const float* c1w  = (const float*)d_in[1];
  const float* c1b  = (const float*)d_in[2];
  const float* pw   = (const float*)d_in[3];
  const float* pb   = (const float*)d_in[4];
  const float* Wdc  = (const float*)d_in[5];
  const float* w1   = (const float*)d_in[6];
  const float* b1   = (const float*)d_in[7];
  const float* w2   = (const float*)d_in[8];
  const float* b2   = (const float*)d_in[9];
  const float* w3   = (const float*)d_in[10];
  const float* b3   = (const float*)d_in[11];
  float* out = (float*)d_out;
  float* ws  = (float*)d_ws;

  float* WT   = ws + OFF_WT;
  float* X1   = ws + OFF_X1;
  float* PU   = ws + OFF_PU;
  float* UHAT = ws + OFF_UHAT;
  float* U    = ws + OFF_U;
  float* BIJ  = ws + OFF_BIJ;
  float* CIJ  = ws + OFF_CIJ;
  float* SP   = ws + OFF_SP;
  float* VJ   = ws + OFF_VJ;
  int*   IDX  = (int*)(ws + OFF_IDX);
  float* H1   = ws + OFF_H1;
  float* H2   = ws + OFF_H2;

  k_transpose_w<<<dim3(256, 4), 256, 0, stream>>>(pw, WT);
  k_conv1<<<dim3(BATCH, 8), 256, 0, stream>>>(data, c1w, c1b, X1);
  k_prim<<<dim3(4, 8, 25), 512, 0, stream>>>(X1, WT, PU);
  k_ured<<<1600, 256, 0, stream>>>(PU, pb, U);
  k_squash<<<BATCH, 256, 0, stream>>>(U);                     // U -> u_sq in place
  k_uhat<<<256, 192, 0, stream>>>(Wdc, U, UHAT);              // clobbers WT/X1/PU (dead)
  k_zero<<<80, 256, 0, stream>>>(BIJ, 20480);

  for (int it = 0; it < 3; ++it) {
    k_softc<<<10, 256, 0, stream>>>(BIJ, CIJ);
    k_sjpart<<<dim3(BATCH, 16), 192, 0, stream>>>(CIJ, UHAT, SP);
    k_sjred<<<BATCH, 192, 0, stream>>>(SP, VJ, out, it == 2 ? 1 : 0);
    if (it < 2) k_amean<<<256, 192, 0, stream>>>(UHAT, VJ, BIJ);
  }

  k_cls<<<1, 256, 0, stream>>>(VJ, IDX);
  k_dec1<<<BATCH, 256, 0, stream>>>(w1, b1, VJ, IDX, H1);
  k_dec2<<<dim3(16, 25), 256, 0, stream>>>(w2, b2, H1, H2);
  k_dec3<<<dim3(16, 25), 256, 0, stream>>>(w3, b3, H2, out);
}

// Round 4
// 1544.347 us; speedup vs baseline: 1.0972x; 1.0972x over previous
//
#include <hip/hip_runtime.h>
#include <cstdint>
#include <cstddef>

// ---------------------------------------------------------------------------
// CapsNet forward, f32 end-to-end (precision-critical: the sort-based squash
// flips discrete segments on ~1e-7 perturbations of s_j, so no bf16 on that
// path).
//
// Workspace phases (floats), peak footprint 34,799,616 fl = 132.7 MiB:
//   A (prim):    WT[0..5.31M] X1[5.31..20.05M] PU[20.05..33.16M]
//   B (ured):    U[33.16..34.80M]
//   C (uhat):    UHAT[0..32.77M] + U
//   D (routing): UHAT + smalls[32.77M..33.23M] (overlaying dead PU tail / U)
// ---------------------------------------------------------------------------

#define BATCH 100

static const size_t OFF_WT   = 0;            // 256*81*256 = 5,308,416   (dead after prim)
static const size_t OFF_X1   = 5308416;      // 100*256*576 = 14,745,600 (dead after prim)
static const size_t OFF_PU   = 20054016;     // 8*100*2048*8 = 13,107,200 (dead after k_ured)
static const size_t OFF_UHAT = 0;            // 100*2048*160 = 32,768,000
static const size_t OFF_U    = 33161216;     // 100*2048*8 = 1,638,400 (dead after k_uhat)
static const size_t OFF_BIJ  = 32768000;     // 2048*10                (dead after last softc)
static const size_t OFF_CIJ  = 32788480;     // 2048*10                (dead after last sjpart)
static const size_t OFF_SP   = 32808960;     // 100*16*160 = 256,000   (dead after last sjred)
static const size_t OFF_VJ   = 33064960;     // 100*160
static const size_t OFF_IDX  = 33080960;     // 100 ints (128 slots)   (post-routing only)
static const size_t OFF_H1   = 33081088;     // 100*512                (post-routing only)
static const size_t OFF_H2   = 33132288;     // 100*1024 -> end 33,234,688 (overlaps dead U tail)

// piecewise-affine squash constants
#define PT1f -13.46416092f
#define PA1f 0.000242759f
#define PB1f 0.024488359f
#define PA2f 0.002769205f
#define PB2f 0.06089699f
#define PT3f 13.23405266f
#define PA3f -0.002828244f
#define PB3f 0.061313814f
#define PA4f -0.000219038f
#define PB4f 0.023874787f

#define DT1f -0.075410217f
#define DA1f -0.074520095f
#define DB1f 0.349297946f
#define DA2f -0.534473989f
#define DB2f 0.27196494f
#define DT3f 0.062207676f
#define DA3f 0.637642944f
#define DB3f 0.295330779f
#define DA4f 0.169344703f
#define DB4f 0.353784456f

// ---------------------------------------------------------------------------
// w_t[(ci*81+tap)*256 + co]  <-  prim_w[co][ci][tap]
// ---------------------------------------------------------------------------
__global__ __launch_bounds__(256)
void k_transpose_w(const float* __restrict__ w, float* __restrict__ wt) {
  __shared__ float tile[64 * 82];
  int ci = blockIdx.x, co0 = blockIdx.y * 64, t = threadIdx.x;
  for (int f = t; f < 64 * 81; f += 256) {
    int col = f / 81, tap = f - col * 81;
    tile[col * 82 + tap] = w[(size_t)(co0 + col) * 20736 + (size_t)ci * 81 + tap];
  }
  __syncthreads();
  for (int g = t; g < 64 * 81; g += 256) {
    int tap = g / 64, col = g - tap * 64;
    wt[((size_t)ci * 81 + tap) * 256 + co0 + col] = tile[col * 82 + tap];
  }
}

// ---------------------------------------------------------------------------
// conv1 + bias + relu: data(100,1,32,32) -> x1(100,256,24,24)
// ---------------------------------------------------------------------------
__global__ __launch_bounds__(256)
void k_conv1(const float* __restrict__ data, const float* __restrict__ cw,
             const float* __restrict__ cb, float* __restrict__ x1) {
  __shared__ float img[1024];
  __shared__ float wl[81 * 32];     // [tap][c]
  int b = blockIdx.x, cg = blockIdx.y, t = threadIdx.x;
  for (int f = t; f < 1024; f += 256) img[f] = data[(size_t)b * 1024 + f];
  for (int f = t; f < 2592; f += 256) {
    int tap = f >> 5, c = f & 31;
    wl[f] = cw[(size_t)(cg * 32 + c) * 81 + tap];
  }
  __syncthreads();
  for (int task = t; task < 1152; task += 256) {
    int q = task % 144, cq = task / 144;
    int p0 = q * 4, oh = p0 / 24, ow0 = p0 % 24;
    float a[4][4];
#pragma unroll
    for (int i = 0; i < 4; ++i)
#pragma unroll
      for (int j = 0; j < 4; ++j) a[i][j] = 0.f;
    for (int kh = 0; kh < 9; ++kh) {
      const float* ir = &img[(oh + kh) * 32 + ow0];
      const float* wr = &wl[kh * 9 * 32 + cq * 4];
#pragma unroll
      for (int kw = 0; kw < 9; ++kw) {
        float4 wv = *(const float4*)(wr + kw * 32);
#pragma unroll
        for (int j = 0; j < 4; ++j) {
          float xv = ir[kw + j];
          a[0][j] = fmaf(wv.x, xv, a[0][j]);
          a[1][j] = fmaf(wv.y, xv, a[1][j]);
          a[2][j] = fmaf(wv.z, xv, a[2][j]);
          a[3][j] = fmaf(wv.w, xv, a[3][j]);
        }
      }
    }
#pragma unroll
    for (int cc = 0; cc < 4; ++cc) {
      int c = cg * 32 + cq * 4 + cc;
      float bias = cb[c];
      float4 o4 = make_float4(fmaxf(a[cc][0] + bias, 0.f), fmaxf(a[cc][1] + bias, 0.f),
                              fmaxf(a[cc][2] + bias, 0.f), fmaxf(a[cc][3] + bias, 0.f));
      *(float4*)&x1[((size_t)(b * 256 + c) * 24 + oh) * 24 + ow0] = o4;
    }
  }
}

// ---------------------------------------------------------------------------
// prim conv v4: x1(100,256,24,24) -> PU[split](100,2048,8), 9x9 stride 2.
// Block = 256 thr = 2 batches x (8 coq x 16 posq); tile 2b x 32co x 64pos,
// 32 ci per block (8-way ci split -> grid 3200 = 12.5 blk/CU, 4% tail).
// x staged PHASE-SPLIT (even/odd cols): every inner LDS read is ds_read_b128.
// LDS 30 KB -> 5 blocks/CU x 4 waves = 20 waves/CU cap.
// ---------------------------------------------------------------------------
__global__ __launch_bounds__(256, 5)
void k_prim(const float* __restrict__ x1, const float* __restrict__ wt,
            float* __restrict__ pu) {
  __shared__ float wsh[2 * 81 * 32];       // [cil][tap][co32]         20736 B
  __shared__ float xsh[2 * 2 * 2 * 288];   // [tb][cil][phase][24x12]   9216 B
  int t = threadIdx.x;
  int tb = t >> 7, tl = t & 127;
  int coq = tl >> 4, posq = tl & 15;
  int oh = posq >> 1, owq = posq & 1;
  int ci_base = blockIdx.x * 32, cog = blockIdx.y, bpair = blockIdx.z;
  int b = bpair * 2 + tb;

  float acc[4][4];
#pragma unroll
  for (int i = 0; i < 4; ++i)
#pragma unroll
    for (int j = 0; j < 4; ++j) acc[i][j] = 0.f;

#pragma unroll 1
  for (int ci0 = ci_base; ci0 < ci_base + 32; ci0 += 2) {
    __syncthreads();
    // stage x: 576 float4 jobs (2 tb x 2 cil x 144), phase-split on write
    for (int f = t; f < 576; f += 256) {
      int tbj = f / 288, m = f - tbj * 288;
      int cil = m / 144, mm = m - cil * 144;
      int r = mm / 6, mq = mm - r * 6;
      float4 v = *(const float4*)&x1[((size_t)(bpair * 2 + tbj) * 256 + ci0 + cil) * 576 +
                                     r * 24 + mq * 4];
      float* eb = &xsh[((tbj * 2 + cil) * 2 + 0) * 288 + r * 12 + mq * 2];
      *(float2*)eb = make_float2(v.x, v.z);          // even cols 4mq, 4mq+2
      *(float2*)(eb + 288) = make_float2(v.y, v.w);  // odd  cols 4mq+1, 4mq+3
    }
    // stage w: 1296 float4 jobs (2 cil x 81 tap x 8 colq)
    for (int f = t; f < 1296; f += 256) {
      int cil = f / 648, rem = f - cil * 648;
      int tap = rem >> 3, cq = rem & 7;
      float4 v = *(const float4*)&wt[((size_t)(ci0 + cil) * 81 + tap) * 256 +
                                     cog * 32 + cq * 4];
      *(float4*)&wsh[(cil * 81 + tap) * 32 + cq * 4] = v;
    }
    __syncthreads();
#pragma unroll
    for (int cil = 0; cil < 2; ++cil) {
      const float* xb0 = &xsh[((tb * 2 + cil) * 2 + 0) * 288 + owq * 4];
      const float* wb0 = &wsh[cil * 81 * 32 + coq * 4];
#pragma unroll
      for (int kh = 0; kh < 9; ++kh) {
        int r = 2 * oh + kh;
        const float* xe = xb0 + r * 12;
        float e[8], o8[8];
        *(float4*)&e[0]  = *(const float4*)xe;
        *(float4*)&e[4]  = *(const float4*)(xe + 4);
        *(float4*)&o8[0] = *(const float4*)(xe + 288);
        *(float4*)&o8[4] = *(const float4*)(xe + 292);
        const float* wr = wb0 + kh * 9 * 32;
#pragma unroll
        for (int kp = 0; kp < 5; ++kp) {               // kw = 2*kp (even cols)
          float4 wv = *(const float4*)(wr + kp * 64);
#pragma unroll
          for (int j = 0; j < 4; ++j) {
            float xv = e[kp + j];
            acc[0][j] = fmaf(wv.x, xv, acc[0][j]);
            acc[1][j] = fmaf(wv.y, xv, acc[1][j]);
            acc[2][j] = fmaf(wv.z, xv, acc[2][j]);
            acc[3][j] = fmaf(wv.w, xv, acc[3][j]);
          }
        }
#pragma unroll
        for (int kp = 0; kp < 4; ++kp) {               // kw = 2*kp+1 (odd cols)
          float4 wv = *(const float4*)(wr + 32 + kp * 64);
#pragma unroll
          for (int j = 0; j < 4; ++j) {
            float xv = o8[kp + j];
            acc[0][j] = fmaf(wv.x, xv, acc[0][j]);
            acc[1][j] = fmaf(wv.y, xv, acc[1][j]);
            acc[2][j] = fmaf(wv.z, xv, acc[2][j]);
            acc[3][j] = fmaf(wv.w, xv, acc[3][j]);
          }
        }
      }
    }
  }
  // partial write (no bias; k_ured adds it): pu[split][b][r=co*8+oh][ow]
  float* pp = pu + (((size_t)blockIdx.x * BATCH + b) * 2048 +
                    (cog * 32 + coq * 4) * 8 + oh) * 8 + owq * 4;
#pragma unroll
  for (int cc = 0; cc < 4; ++cc) {
    float4 o4 = make_float4(acc[cc][0], acc[cc][1], acc[cc][2], acc[cc][3]);
    *(float4*)(pp + cc * 64) = o4;   // co+1 -> r+8 -> +64 floats
  }
}

// u = sum of 8 partials (ci-ascending order) + bias
__global__ __launch_bounds__(256)
void k_ured(const float* __restrict__ pu, const float* __restrict__ pb,
            float* __restrict__ u) {
  int g4 = blockIdx.x * 256 + threadIdx.x;     // 409,600 float4s
  if (g4 >= 409600) return;
  size_t g = (size_t)g4 * 4;
  const size_t S = 1638400;
  float4 s = *(const float4*)(pu + g);
#pragma unroll
  for (int k = 1; k < 8; ++k) {
    float4 p = *(const float4*)(pu + (size_t)k * S + g);
    s.x += p.x; s.y += p.y; s.z += p.z; s.w += p.w;
  }
  int r = (int)((g >> 3) & 2047);
  float bias = pb[r >> 3];
  float4 o = make_float4(s.x + bias, s.y + bias, s.z + bias, s.w + bias);
  *(float4*)(u + g) = o;
}

// ---------------------------------------------------------------------------
// primary squash: stable bitonic sort per batch row + exact where-chain,
// then u_sq = mag * u in place.
// ---------------------------------------------------------------------------
__global__ __launch_bounds__(256)
void k_squash(float* __restrict__ u) {
  __shared__ float kv[2048];
  __shared__ int kid[2048];
  __shared__ int red[256];
  int b = blockIdx.x, t = threadIdx.x;
  for (int r = t; r < 2048; r += 256) {
    kv[r] = u[((size_t)b * 2048 + r) * 8];
    kid[r] = r;
  }
  __syncthreads();
  for (int size = 2; size <= 2048; size <<= 1) {
    for (int stride = size >> 1; stride > 0; stride >>= 1) {
#pragma unroll 1
      for (int s = 0; s < 4; ++s) {
        int i = t + s * 256;
        int pos = 2 * i - (i & (stride - 1));
        int q = pos + stride;
        float va = kv[pos], vb = kv[q];
        int ia = kid[pos], ib = kid[q];
        bool gt = (va > vb) || (va == vb && ia > ib);
        bool up = ((pos & size) == 0);
        if (gt == up) { kv[pos] = vb; kv[q] = va; kid[pos] = ib; kid[q] = ia; }
      }
      __syncthreads();
    }
  }
  int loc = 0;
#pragma unroll
  for (int s = 0; s < 8; ++s) loc += (kv[t + s * 256] < PT1f) ? 1 : 0;
  red[t] = loc; __syncthreads();
  for (int off = 128; off; off >>= 1) { if (t < off) red[t] += red[t + off]; __syncthreads(); }
  int i1 = red[0]; __syncthreads();
  float m1v[8];
  loc = 0;
#pragma unroll
  for (int s = 0; s < 8; ++s) {
    int p = t + s * 256;
    float v = kv[p];
    float m = (p < i1 - 1) ? (PA1f * v + PB1f) : v;
    m1v[s] = m;
    loc += (m < 0.f) ? 1 : 0;
  }
  red[t] = loc; __syncthreads();
  for (int off = 128; off; off >>= 1) { if (t < off) red[t] += red[t + off]; __syncthreads(); }
  int i2 = red[0]; __syncthreads();
  float m2v[8];
  loc = 0;
#pragma unroll
  for (int s = 0; s < 8; ++s) {
    int p = t + s * 256;
    float m = (p >= i1 && p < i2 - 1) ? (PA2f * m1v[s] + PB2f) : m1v[s];
    m2v[s] = m;
    loc += (m < PT3f) ? 1 : 0;
  }
  red[t] = loc; __syncthreads();
  for (int off = 128; off; off >>= 1) { if (t < off) red[t] += red[t + off]; __syncthreads(); }
  int i3 = red[0]; __syncthreads();
#pragma unroll
  for (int s = 0; s < 8; ++s) {
    int p = t + s * 256;
    float m = m2v[s];
    m = (p >= i2 && p < i3 - 1) ? (PA3f * m + PB3f) : m;
    m = (p >= i3 && p < 2047) ? (PA4f * m + PB4f) : m;
    int rid = kid[p];
    float* row = u + ((size_t)b * 2048 + rid) * 8;
    float4 lo = *(float4*)row;
    float4 hi = *(float4*)(row + 4);
    lo.x *= m; lo.y *= m; lo.z *= m; lo.w *= m;
    hi.x *= m; hi.y *= m; hi.z *= m; hi.w *= m;
    *(float4*)row = lo;
    *(float4*)(row + 4) = hi;
  }
}

// ---------------------------------------------------------------------------
// u_hat[b][r][c*16+o] = sum_i W_dc[r][c][o][i] * u_sq[b][r][i]
// ---------------------------------------------------------------------------
__global__ __launch_bounds__(192)
void k_uhat(const float* __restrict__ Wdc, const float* __restrict__ usq,
            float* __restrict__ uhat) {
  int t = threadIdx.x;
  if (t >= 160) return;
  int r0 = blockIdx.x * 8;
  for (int rl = 0; rl < 8; ++rl) {
    int r = r0 + rl;
    const float* wp = Wdc + ((size_t)r * 160 + t) * 8;
    float4 wa = *(const float4*)wp;
    float4 wb = *(const float4*)(wp + 4);
#pragma unroll 2
    for (int b = 0; b < BATCH; ++b) {
      const float* us = usq + ((size_t)b * 2048 + r) * 8;
      float v = us[0] * wa.x + us[1] * wa.y + us[2] * wa.z + us[3] * wa.w +
                us[4] * wb.x + us[5] * wb.y + us[6] * wb.z + us[7] * wb.w;
      uhat[((size_t)b * 2048 + r) * 160 + t] = v;
    }
  }
}

__global__ void k_zero(float* __restrict__ p, int n) {
  int i = blockIdx.x * blockDim.x + threadIdx.x;
  if (i < n) p[i] = 0.f;
}

__global__ __launch_bounds__(256)
void k_softc(const float* __restrict__ bij, float* __restrict__ cij) {
  __shared__ float red[256];
  int c = blockIdx.x, t = threadIdx.x;
  float m = -3.402823466e38f;
  for (int r = t; r < 2048; r += 256) m = fmaxf(m, bij[r * 10 + c]);
  red[t] = m; __syncthreads();
  for (int off = 128; off; off >>= 1) { if (t < off) red[t] = fmaxf(red[t], red[t + off]); __syncthreads(); }
  m = red[0]; __syncthreads();
  float s = 0.f;
  for (int r = t; r < 2048; r += 256) s += expf(bij[r * 10 + c] - m);
  red[t] = s; __syncthreads();
  for (int off = 128; off; off >>= 1) { if (t < off) red[t] += red[t + off]; __syncthreads(); }
  s = red[0];
  for (int r = t; r < 2048; r += 256) cij[r * 10 + c] = expf(bij[r * 10 + c] - m) / s;
}

__global__ __launch_bounds__(192)
void k_sjpart(const float* __restrict__ cij, const float* __restrict__ uhat,
              float* __restrict__ sp) {
  __shared__ float cl[1280];
  int b = blockIdx.x, ch = blockIdx.y, t = threadIdx.x;
  for (int f = t; f < 1280; f += 192) cl[f] = cij[(size_t)ch * 1280 + f];
  __syncthreads();
  if (t < 160) {
    int c = t >> 4;
    float acc = 0.f;
    const float* up = uhat + ((size_t)b * 2048 + ch * 128) * 160 + t;
#pragma unroll 4
    for (int rl = 0; rl < 128; ++rl) acc += cl[rl * 10 + c] * up[(size_t)rl * 160];
    sp[((size_t)b * 16 + ch) * 160 + t] = acc;
  }
}

__global__ __launch_bounds__(192)
void k_sjred(const float* __restrict__ sp, float* __restrict__ vj,
             float* __restrict__ dout, int finalit) {
  __shared__ float sl[160];
  __shared__ float fl[10];
  int b = blockIdx.x, t = threadIdx.x;
  if (t < 160) {
    float a = 0.f;
#pragma unroll
    for (int ch = 0; ch < 16; ++ch) a += sp[((size_t)b * 16 + ch) * 160 + t];
    sl[t] = a;
  }
  __syncthreads();
  if (t == 0) {
    float sv[10]; int rk[10];
    for (int c = 0; c < 10; ++c) sv[c] = sl[c * 16];
    for (int c = 0; c < 10; ++c) {
      int r = 0;
      for (int k = 0; k < 10; ++k)
        r += ((sv[k] < sv[c]) || (sv[k] == sv[c] && k < c)) ? 1 : 0;
      rk[c] = r;
    }
    int i1 = 0;
    for (int c = 0; c < 10; ++c) i1 += (sv[c] < DT1f) ? 1 : 0;
    float m1[10];
    for (int c = 0; c < 10; ++c) m1[c] = (rk[c] < i1 - 1) ? (DA1f * sv[c] + DB1f) : sv[c];
    int i2 = 0;
    for (int c = 0; c < 10; ++c) i2 += (m1[c] < 0.f) ? 1 : 0;
    float m2[10];
    for (int c = 0; c < 10; ++c)
      m2[c] = (rk[c] >= i1 && rk[c] < i2 - 1) ? (DA2f * m1[c] + DB2f) : m1[c];
    int i3 = 0;
    for (int c = 0; c < 10; ++c) i3 += (m2[c] < DT3f) ? 1 : 0;
    for (int c = 0; c < 10; ++c) {
      float m = (rk[c] >= i2 && rk[c] < i3 - 1) ? (DA3f * m2[c] + DB3f) : m2[c];
      m = (rk[c] >= i3 && rk[c] < 9) ? (DA4f * m + DB4f) : m;
      fl[c] = m;
    }
  }
  __syncthreads();
  if (t < 160) {
    int c = t >> 4, o = t & 15;
    float fv = fl[c];
    float v = fv * ((o == 0) ? fv : sl[t]);
    vj[(size_t)b * 160 + t] = v;
    if (finalit) dout[(size_t)b * 1184 + t] = v;
  }
}

__global__ __launch_bounds__(192)
void k_amean(const float* __restrict__ uhat, const float* __restrict__ vj,
             float* __restrict__ bij) {
  __shared__ float vl[16000];
  int t = threadIdx.x, r0 = blockIdx.x * 8;
  for (int f = t; f < 16000; f += 192) vl[f] = vj[f];
  __syncthreads();
  if (t < 160) {
    int c = t >> 4;
    for (int rl = 0; rl < 8; ++rl) {
      int r = r0 + rl;
      float acc = 0.f;
      const float* up = uhat + (size_t)r * 160 + t;
#pragma unroll 4
      for (int b = 0; b < BATCH; ++b) acc += up[(size_t)b * 2048 * 160] * vl[b * 160 + t];
      for (int off = 8; off; off >>= 1) acc += __shfl_down(acc, off, 16);
      if ((t & 15) == 0) bij[r * 10 + c] += acc / 100.0f;
    }
  }
}

__global__ __launch_bounds__(256)
void k_cls(const float* __restrict__ vj, int* __restrict__ idxg) {
  __shared__ float cl[1000];
  __shared__ float cm[10];
  __shared__ float cs[10];
  int t = threadIdx.x;
  for (int f = t; f < 1000; f += 256) {
    int b = f / 10, c = f - b * 10;
    float s = 0.f;
#pragma unroll
    for (int o = 0; o < 16; ++o) {
      float v = vj[(size_t)b * 160 + c * 16 + o];
      s += v * v;
    }
    cl[f] = sqrtf(s);
  }
  __syncthreads();
  if (t < 10) {
    float m = -3.402823466e38f;
    for (int b = 0; b < BATCH; ++b) m = fmaxf(m, cl[b * 10 + t]);
    float s = 0.f;
    for (int b = 0; b < BATCH; ++b) s += expf(cl[b * 10 + t] - m);
    cm[t] = m; cs[t] = s;
  }
  __syncthreads();
  for (int b = t; b < BATCH; b += 256) {
    float best = -1.f; int bi = 0;
    for (int c = 0; c < 10; ++c) {
      float val = expf(cl[b * 10 + c] - cm[c]) / cs[c];
      if (val > best) { best = val; bi = c; }
    }
    idxg[b] = bi;
  }
}

__global__ __launch_bounds__(256)
void k_dec1(const float* __restrict__ w1, const float* __restrict__ b1,
            const float* __restrict__ vj, const int* __restrict__ idxg,
            float* __restrict__ h1) {
  int b = blockIdx.x, t = threadIdx.x;
  int id = idxg[b];
  const float* v = vj + (size_t)b * 160 + id * 16;
  for (int j = t; j < 512; j += 256) {
    float acc = b1[j];
    const float* wr = w1 + (size_t)j * 160 + id * 16;
#pragma unroll
    for (int o = 0; o < 16; ++o) acc += wr[o] * v[o];
    h1[(size_t)b * 512 + j] = fmaxf(acc, 0.f);
  }
}

__global__ __launch_bounds__(256)
void k_dec2(const float* __restrict__ w2, const float* __restrict__ b2,
            const float* __restrict__ h1, float* __restrict__ h2) {
  __shared__ float red[4][64][4];
  int t = threadIdx.x, lane = t & 63, strip = t >> 6;
  int j = blockIdx.x * 64 + lane, bs = blockIdx.y * 4;
  float acc[4] = {0.f, 0.f, 0.f, 0.f};
  const float* wr = w2 + (size_t)j * 512 + strip * 128;
  const float* hb = h1 + (size_t)bs * 512 + strip * 128;
  for (int k4 = 0; k4 < 32; ++k4) {
    float4 wv = *(const float4*)(wr + k4 * 4);
    const float* h0 = hb + k4 * 4;
#pragma unroll
    for (int q = 0; q < 4; ++q) {
      float4 hv = *(const float4*)(h0 + q * 512);
      acc[q] += wv.x * hv.x + wv.y * hv.y + wv.z * hv.z + wv.w * hv.w;
    }
  }
#pragma unroll
  for (int q = 0; q < 4; ++q) red[strip][lane][q] = acc[q];
  __syncthreads();
  if (strip == 0) {
    float bias = b2[j];
#pragma unroll
    for (int q = 0; q < 4; ++q) {
      float tot = red[0][lane][q] + red[1][lane][q] + red[2][lane][q] + red[3][lane][q] + bias;
      h2[(size_t)(bs + q) * 1024 + j] = fmaxf(tot, 0.f);
    }
  }
}

__global__ __launch_bounds__(256)
void k_dec3(const float* __restrict__ w3, const float* __restrict__ b3,
            const float* __restrict__ h2, float* __restrict__ dout) {
  __shared__ float red[4][64][4];
  int t = threadIdx.x, lane = t & 63, strip = t >> 6;
  int j = blockIdx.x * 64 + lane, bs = blockIdx.y * 4;
  float acc[4] = {0.f, 0.f, 0.f, 0.f};
  const float* wr = w3 + (size_t)j * 1024 + strip * 256;
  const float* hb = h2 + (size_t)bs * 1024 + strip * 256;
  for (int k4 = 0; k4 < 64; ++k4) {
    float4 wv = *(const float4*)(wr + k4 * 4);
    const float* h0 = hb + k4 * 4;
#pragma unroll
    for (int q = 0; q < 4; ++q) {
      float4 hv = *(const float4*)(h0 + q * 1024);
      acc[q] += wv.x * hv.x + wv.y * hv.y + wv.z * hv.z + wv.w * hv.w;
    }
  }
#pragma unroll
  for (int q = 0; q < 4; ++q) red[strip][lane][q] = acc[q];
  __syncthreads();
  if (strip == 0) {
    float bias = b3[j];
#pragma unroll
    for (int q = 0; q < 4; ++q) {
      float tot = red[0][lane][q] + red[1][lane][q] + red[2][lane][q] + red[3][lane][q] + bias;
      dout[(size_t)(bs + q) * 1184 + 160 + j] = 1.f / (1.f + expf(-tot));
    }
  }
}

// ---------------------------------------------------------------------------
extern "C" void kernel_launch(void* const* d_in, const int* in_sizes, int n_in,
                              void* d_out, int out_size, void* d_ws, size_t ws_size,
                              hipStream_t stream) {
  (void)in_sizes; (void)n_in; (void)out_size; (void)ws_size;
  const float* data = (const float*)d_in[0];
  const float* c1w  = (const float*)d_in[1];
  const float* c1b  = (const float*)d_in[2];
  const float* pw   = (const float*)d_in[3];
  const float* pb   = (const float*)d_in[4];
  const float* Wdc  = (const float*)d_in[5];
  const float* w1   = (const float*)d_in[6];
  const float* b1   = (const float*)d_in[7];
  const float* w2   = (const float*)d_in[8];
  const float* b2   = (const float*)d_in[9];
  const float* w3   = (const float*)d_in[10];
  const float* b3   = (const float*)d_in[11];
  float* out = (float*)d_out;
  float* ws  = (float*)d_ws;

  float* WT   = ws + OFF_WT;
  float* X1   = ws + OFF_X1;
  float* PU   = ws + OFF_PU;
  float* UHAT = ws + OFF_UHAT;
  float* U    = ws + OFF_U;
  float* BIJ  = ws + OFF_BIJ;
  float* CIJ  = ws + OFF_CIJ;
  float* SP   = ws + OFF_SP;
  float* VJ   = ws + OFF_VJ;
  int*   IDX  = (int*)(ws + OFF_IDX);
  float* H1   = ws + OFF_H1;
  float* H2   = ws + OFF_H2;

  k_transpose_w<<<dim3(256, 4), 256, 0, stream>>>(pw, WT);
  k_conv1<<<dim3(BATCH, 8), 256, 0, stream>>>(data, c1w, c1b, X1);
  k_prim<<<dim3(8, 8, 50), 256, 0, stream>>>(X1, WT, PU);
  k_ured<<<1600, 256, 0, stream>>>(PU, pb, U);
  k_squash<<<BATCH, 256, 0, stream>>>(U);                     // U -> u_sq in place
  k_uhat<<<256, 192, 0, stream>>>(Wdc, U, UHAT);              // clobbers WT/X1/PU (dead)
  k_zero<<<80, 256, 0, stream>>>(BIJ, 20480);

  for (int it = 0; it < 3; ++it) {
    k_softc<<<10, 256, 0, stream>>>(BIJ, CIJ);
    k_sjpart<<<dim3(BATCH, 16), 192, 0, stream>>>(CIJ, UHAT, SP);
    k_sjred<<<BATCH, 192, 0, stream>>>(SP, VJ, out, it == 2 ? 1 : 0);
    if (it < 2) k_amean<<<256, 192, 0, stream>>>(UHAT, VJ, BIJ);
  }

  k_cls<<<1, 256, 0, stream>>>(VJ, IDX);
  k_dec1<<<BATCH, 256, 0, stream>>>(w1, b1, VJ, IDX, H1);
  k_dec2<<<dim3(16, 25), 256, 0, stream>>>(w2, b2, H1, H2);
  k_dec3<<<dim3(16, 25), 256, 0, stream>>>(w3, b3, H2, out);
}

// Round 5
// 1459.692 us; speedup vs baseline: 1.1609x; 1.0580x over previous
//
#include <hip/hip_runtime.h>
#include <cstdint>
#include <cstddef>

// ---------------------------------------------------------------------------
// CapsNet forward, f32 end-to-end (precision-critical: the sort-based squash
// flips discrete segments on ~1e-7 perturbations of s_j, so no bf16 on that
// path).
//
// Workspace phases (floats), peak footprint 33.2M fl (proven <= ws):
//   A (prim):    WT[0..5.31M] X1[5.31..20.05M] PU[20.05..33.16M]
//   B (ured):    U[33.16..34.80M]
//   C (uhat):    UHAT[0..32.77M] + U
//   D (routing): UHAT + smalls[32.77M..33.23M]
// ---------------------------------------------------------------------------

#define BATCH 100

static const size_t OFF_WT   = 0;            // 256*81*256 = 5,308,416   (dead after prim)
static const size_t OFF_X1   = 5308416;      // 100*256*576 = 14,745,600 (dead after prim)
static const size_t OFF_PU   = 20054016;     // 8*100*2048*8 = 13,107,200 (dead after k_ured)
static const size_t OFF_UHAT = 0;            // 100*2048*160 = 32,768,000
static const size_t OFF_U    = 33161216;     // 100*2048*8 = 1,638,400 (dead after k_uhat)
static const size_t OFF_BIJ  = 32768000;     // 2048*10
static const size_t OFF_CIJ  = 32788480;     // 2048*10
static const size_t OFF_SP   = 32808960;     // 100*16*160 = 256,000
static const size_t OFF_VJ   = 33064960;     // 100*160
static const size_t OFF_IDX  = 33080960;     // 100 ints (128 slots)
static const size_t OFF_H1   = 33081088;     // 100*512
static const size_t OFF_H2   = 33132288;     // 100*1024 -> end 33,234,688

// piecewise-affine squash constants
#define PT1f -13.46416092f
#define PA1f 0.000242759f
#define PB1f 0.024488359f
#define PA2f 0.002769205f
#define PB2f 0.06089699f
#define PT3f 13.23405266f
#define PA3f -0.002828244f
#define PB3f 0.061313814f
#define PA4f -0.000219038f
#define PB4f 0.023874787f

#define DT1f -0.075410217f
#define DA1f -0.074520095f
#define DB1f 0.349297946f
#define DA2f -0.534473989f
#define DB2f 0.27196494f
#define DT3f 0.062207676f
#define DA3f 0.637642944f
#define DB3f 0.295330779f
#define DA4f 0.169344703f
#define DB4f 0.353784456f

// ---------------------------------------------------------------------------
// w_t[(ci*81+tap)*256 + co]  <-  prim_w[co][ci][tap]
// ---------------------------------------------------------------------------
__global__ __launch_bounds__(256)
void k_transpose_w(const float* __restrict__ w, float* __restrict__ wt) {
  __shared__ float tile[64 * 82];
  int ci = blockIdx.x, co0 = blockIdx.y * 64, t = threadIdx.x;
  for (int f = t; f < 64 * 81; f += 256) {
    int col = f / 81, tap = f - col * 81;
    tile[col * 82 + tap] = w[(size_t)(co0 + col) * 20736 + (size_t)ci * 81 + tap];
  }
  __syncthreads();
  for (int g = t; g < 64 * 81; g += 256) {
    int tap = g / 64, col = g - tap * 64;
    wt[((size_t)ci * 81 + tap) * 256 + co0 + col] = tile[col * 82 + tap];
  }
}

// ---------------------------------------------------------------------------
// conv1 + bias + relu: data(100,1,32,32) -> x1(100,256,24,24)
// ---------------------------------------------------------------------------
__global__ __launch_bounds__(256)
void k_conv1(const float* __restrict__ data, const float* __restrict__ cw,
             const float* __restrict__ cb, float* __restrict__ x1) {
  __shared__ float img[1024];
  __shared__ float wl[81 * 32];     // [tap][c]
  int b = blockIdx.x, cg = blockIdx.y, t = threadIdx.x;
  for (int f = t; f < 1024; f += 256) img[f] = data[(size_t)b * 1024 + f];
  for (int f = t; f < 2592; f += 256) {
    int tap = f >> 5, c = f & 31;
    wl[f] = cw[(size_t)(cg * 32 + c) * 81 + tap];
  }
  __syncthreads();
  for (int task = t; task < 1152; task += 256) {
    int q = task % 144, cq = task / 144;
    int p0 = q * 4, oh = p0 / 24, ow0 = p0 % 24;
    float a[4][4];
#pragma unroll
    for (int i = 0; i < 4; ++i)
#pragma unroll
      for (int j = 0; j < 4; ++j) a[i][j] = 0.f;
    for (int kh = 0; kh < 9; ++kh) {
      const float* ir = &img[(oh + kh) * 32 + ow0];
      const float* wr = &wl[kh * 9 * 32 + cq * 4];
#pragma unroll
      for (int kw = 0; kw < 9; ++kw) {
        float4 wv = *(const float4*)(wr + kw * 32);
#pragma unroll
        for (int j = 0; j < 4; ++j) {
          float xv = ir[kw + j];
          a[0][j] = fmaf(wv.x, xv, a[0][j]);
          a[1][j] = fmaf(wv.y, xv, a[1][j]);
          a[2][j] = fmaf(wv.z, xv, a[2][j]);
          a[3][j] = fmaf(wv.w, xv, a[3][j]);
        }
      }
    }
#pragma unroll
    for (int cc = 0; cc < 4; ++cc) {
      int c = cg * 32 + cq * 4 + cc;
      float bias = cb[c];
      float4 o4 = make_float4(fmaxf(a[cc][0] + bias, 0.f), fmaxf(a[cc][1] + bias, 0.f),
                              fmaxf(a[cc][2] + bias, 0.f), fmaxf(a[cc][3] + bias, 0.f));
      *(float4*)&x1[((size_t)(b * 256 + c) * 24 + oh) * 24 + ow0] = o4;
    }
  }
}

// ---------------------------------------------------------------------------
// prim conv v5: x1(100,256,24,24) -> PU[split](100,2048,8), 9x9 stride 2.
// Block = 256 thr = 4 batches x (8 coq x 8 oh); thread tile 4co x 8ow (full
// output row). 32 ci per block (8-way ci split), cil=1 staging.
// x phase-split (even/odd cols); staging jobs pack 8 cols -> one even float4
// + one odd float4: both LDS stores are DENSE b128 (conflict-free).
// Inner: per (ci,kh) 288 FMA vs 15 b128 (2x FMA density of v4).
// Per-output FMA order identical to v4 -> bitwise-same partials.
// LDS 19.6 KB; VGPR cap 102 (5 waves/EU).
// ---------------------------------------------------------------------------
__global__ __launch_bounds__(256, 5)
void k_prim(const float* __restrict__ x1, const float* __restrict__ wt,
            float* __restrict__ pu) {
  __shared__ float wsh[81 * 32];        // [tap][co32]               10368 B
  __shared__ float xsh[4 * 2 * 288];    // [tb][phase][24 rows x 12]  9216 B
  int t = threadIdx.x;
  int tb = t >> 6, tl = t & 63;
  int coq = tl >> 3, oh = tl & 7;
  int ci_base = blockIdx.x * 32, cog = blockIdx.y, bq = blockIdx.z;
  int b = bq * 4 + tb;

  float acc[4][8];
#pragma unroll
  for (int i = 0; i < 4; ++i)
#pragma unroll
    for (int j = 0; j < 8; ++j) acc[i][j] = 0.f;

#pragma unroll 1
  for (int ci = ci_base; ci < ci_base + 32; ++ci) {
    __syncthreads();
    // stage x: 288 jobs (4 tb x 24 rows x 3 col-octs); each job: 8 cols ->
    // 1 even float4 + 1 odd float4 (dense b128 stores, conflict-free)
    for (int f = t; f < 288; f += 256) {
      int tbj = f / 72, rem = f - tbj * 72;
      int r = rem / 3, oct = rem - r * 3;
      const float* gp = &x1[((size_t)(bq * 4 + tbj) * 256 + ci) * 576 + r * 24 + oct * 8];
      float4 v1 = *(const float4*)gp;
      float4 v2 = *(const float4*)(gp + 4);
      float* eb = &xsh[tbj * 576 + r * 12 + oct * 4];
      *(float4*)eb = make_float4(v1.x, v1.z, v2.x, v2.z);          // even cols
      *(float4*)(eb + 288) = make_float4(v1.y, v1.w, v2.y, v2.w);  // odd cols
    }
    // stage w: 648 float4 jobs (81 tap x 8 colq) — dense b128 stores
    for (int f = t; f < 648; f += 256) {
      int tap = f >> 3, cq = f & 7;
      float4 v = *(const float4*)&wt[((size_t)ci * 81 + tap) * 256 + cog * 32 + cq * 4];
      *(float4*)&wsh[tap * 32 + cq * 4] = v;
    }
    __syncthreads();
    const float* xb = &xsh[tb * 576];
    const float* wb = &wsh[coq * 4];
#pragma unroll 3
    for (int kh = 0; kh < 9; ++kh) {
      int r = 2 * oh + kh;
      const float* xe = xb + r * 12;
      float ew[12], ov[12];
      *(float4*)&ew[0] = *(const float4*)xe;
      *(float4*)&ew[4] = *(const float4*)(xe + 4);
      *(float4*)&ew[8] = *(const float4*)(xe + 8);
      *(float4*)&ov[0] = *(const float4*)(xe + 288);
      *(float4*)&ov[4] = *(const float4*)(xe + 292);
      *(float4*)&ov[8] = *(const float4*)(xe + 296);
      const float* wr = wb + kh * 9 * 32;
#pragma unroll
      for (int p = 0; p < 5; ++p) {                 // kw = 2p (even cols)
        float4 wv = *(const float4*)(wr + p * 64);
#pragma unroll
        for (int j = 0; j < 8; ++j) {
          float xv = ew[p + j];
          acc[0][j] = fmaf(wv.x, xv, acc[0][j]);
          acc[1][j] = fmaf(wv.y, xv, acc[1][j]);
          acc[2][j] = fmaf(wv.z, xv, acc[2][j]);
          acc[3][j] = fmaf(wv.w, xv, acc[3][j]);
        }
      }
#pragma unroll
      for (int p = 0; p < 4; ++p) {                 // kw = 2p+1 (odd cols)
        float4 wv = *(const float4*)(wr + 32 + p * 64);
#pragma unroll
        for (int j = 0; j < 8; ++j) {
          float xv = ov[p + j];
          acc[0][j] = fmaf(wv.x, xv, acc[0][j]);
          acc[1][j] = fmaf(wv.y, xv, acc[1][j]);
          acc[2][j] = fmaf(wv.z, xv, acc[2][j]);
          acc[3][j] = fmaf(wv.w, xv, acc[3][j]);
        }
      }
    }
  }
  // partial write (no bias; k_ured adds it): pu[split][b][r=co*8+oh][ow]
  float* pp = pu + (((size_t)blockIdx.x * BATCH + b) * 2048 +
                    (cog * 32 + coq * 4) * 8 + oh) * 8;
#pragma unroll
  for (int cc = 0; cc < 4; ++cc) {
    *(float4*)(pp + cc * 64)     = make_float4(acc[cc][0], acc[cc][1], acc[cc][2], acc[cc][3]);
    *(float4*)(pp + cc * 64 + 4) = make_float4(acc[cc][4], acc[cc][5], acc[cc][6], acc[cc][7]);
  }
}

// u = sum of 8 partials (ci-ascending order) + bias
__global__ __launch_bounds__(256)
void k_ured(const float* __restrict__ pu, const float* __restrict__ pb,
            float* __restrict__ u) {
  int g4 = blockIdx.x * 256 + threadIdx.x;     // 409,600 float4s
  if (g4 >= 409600) return;
  size_t g = (size_t)g4 * 4;
  const size_t S = 1638400;
  float4 s = *(const float4*)(pu + g);
#pragma unroll
  for (int k = 1; k < 8; ++k) {
    float4 p = *(const float4*)(pu + (size_t)k * S + g);
    s.x += p.x; s.y += p.y; s.z += p.z; s.w += p.w;
  }
  int r = (int)((g >> 3) & 2047);
  float bias = pb[r >> 3];
  float4 o = make_float4(s.x + bias, s.y + bias, s.z + bias, s.w + bias);
  *(float4*)(u + g) = o;
}

// ---------------------------------------------------------------------------
// primary squash: stable bitonic sort per batch row + exact where-chain,
// then u_sq = mag * u in place.
// ---------------------------------------------------------------------------
__global__ __launch_bounds__(256)
void k_squash(float* __restrict__ u) {
  __shared__ float kv[2048];
  __shared__ int kid[2048];
  __shared__ int red[256];
  int b = blockIdx.x, t = threadIdx.x;
  for (int r = t; r < 2048; r += 256) {
    kv[r] = u[((size_t)b * 2048 + r) * 8];
    kid[r] = r;
  }
  __syncthreads();
  for (int size = 2; size <= 2048; size <<= 1) {
    for (int stride = size >> 1; stride > 0; stride >>= 1) {
#pragma unroll 1
      for (int s = 0; s < 4; ++s) {
        int i = t + s * 256;
        int pos = 2 * i - (i & (stride - 1));
        int q = pos + stride;
        float va = kv[pos], vb = kv[q];
        int ia = kid[pos], ib = kid[q];
        bool gt = (va > vb) || (va == vb && ia > ib);
        bool up = ((pos & size) == 0);
        if (gt == up) { kv[pos] = vb; kv[q] = va; kid[pos] = ib; kid[q] = ia; }
      }
      __syncthreads();
    }
  }
  int loc = 0;
#pragma unroll
  for (int s = 0; s < 8; ++s) loc += (kv[t + s * 256] < PT1f) ? 1 : 0;
  red[t] = loc; __syncthreads();
  for (int off = 128; off; off >>= 1) { if (t < off) red[t] += red[t + off]; __syncthreads(); }
  int i1 = red[0]; __syncthreads();
  float m1v[8];
  loc = 0;
#pragma unroll
  for (int s = 0; s < 8; ++s) {
    int p = t + s * 256;
    float v = kv[p];
    float m = (p < i1 - 1) ? (PA1f * v + PB1f) : v;
    m1v[s] = m;
    loc += (m < 0.f) ? 1 : 0;
  }
  red[t] = loc; __syncthreads();
  for (int off = 128; off; off >>= 1) { if (t < off) red[t] += red[t + off]; __syncthreads(); }
  int i2 = red[0]; __syncthreads();
  float m2v[8];
  loc = 0;
#pragma unroll
  for (int s = 0; s < 8; ++s) {
    int p = t + s * 256;
    float m = (p >= i1 && p < i2 - 1) ? (PA2f * m1v[s] + PB2f) : m1v[s];
    m2v[s] = m;
    loc += (m < PT3f) ? 1 : 0;
  }
  red[t] = loc; __syncthreads();
  for (int off = 128; off; off >>= 1) { if (t < off) red[t] += red[t + off]; __syncthreads(); }
  int i3 = red[0]; __syncthreads();
#pragma unroll
  for (int s = 0; s < 8; ++s) {
    int p = t + s * 256;
    float m = m2v[s];
    m = (p >= i2 && p < i3 - 1) ? (PA3f * m + PB3f) : m;
    m = (p >= i3 && p < 2047) ? (PA4f * m + PB4f) : m;
    int rid = kid[p];
    float* row = u + ((size_t)b * 2048 + rid) * 8;
    float4 lo = *(float4*)row;
    float4 hi = *(float4*)(row + 4);
    lo.x *= m; lo.y *= m; lo.z *= m; lo.w *= m;
    hi.x *= m; hi.y *= m; hi.z *= m; hi.w *= m;
    *(float4*)row = lo;
    *(float4*)(row + 4) = hi;
  }
}

// ---------------------------------------------------------------------------
// u_hat[b][r][c*16+o] = sum_i W_dc[r][c][o][i] * u_sq[b][r][i]
// ---------------------------------------------------------------------------
__global__ __launch_bounds__(192)
void k_uhat(const float* __restrict__ Wdc, const float* __restrict__ usq,
            float* __restrict__ uhat) {
  int t = threadIdx.x;
  if (t >= 160) return;
  int r0 = blockIdx.x * 8;
  for (int rl = 0; rl < 8; ++rl) {
    int r = r0 + rl;
    const float* wp = Wdc + ((size_t)r * 160 + t) * 8;
    float4 wa = *(const float4*)wp;
    float4 wb = *(const float4*)(wp + 4);
#pragma unroll 2
    for (int b = 0; b < BATCH; ++b) {
      const float* us = usq + ((size_t)b * 2048 + r) * 8;
      float v = us[0] * wa.x + us[1] * wa.y + us[2] * wa.z + us[3] * wa.w +
                us[4] * wb.x + us[5] * wb.y + us[6] * wb.z + us[7] * wb.w;
      uhat[((size_t)b * 2048 + r) * 160 + t] = v;
    }
  }
}

__global__ __launch_bounds__(256)
void k_softc(const float* __restrict__ bij, float* __restrict__ cij) {
  __shared__ float red[256];
  int c = blockIdx.x, t = threadIdx.x;
  float m = -3.402823466e38f;
  for (int r = t; r < 2048; r += 256) m = fmaxf(m, bij[r * 10 + c]);
  red[t] = m; __syncthreads();
  for (int off = 128; off; off >>= 1) { if (t < off) red[t] = fmaxf(red[t], red[t + off]); __syncthreads(); }
  m = red[0]; __syncthreads();
  float s = 0.f;
  for (int r = t; r < 2048; r += 256) s += expf(bij[r * 10 + c] - m);
  red[t] = s; __syncthreads();
  for (int off = 128; off; off >>= 1) { if (t < off) red[t] += red[t + off]; __syncthreads(); }
  s = red[0];
  for (int r = t; r < 2048; r += 256) cij[r * 10 + c] = expf(bij[r * 10 + c] - m) / s;
}

// it0: c_ij = softmax(zeros) = 1/2048 exactly -> uniform constant, no CIJ read
__global__ __launch_bounds__(192)
void k_sjpart(const float* __restrict__ cij, const float* __restrict__ uhat,
              float* __restrict__ sp, int it0) {
  __shared__ float cl[1280];
  int b = blockIdx.x, ch = blockIdx.y, t = threadIdx.x;
  if (!it0) {
    for (int f = t; f < 1280; f += 192) cl[f] = cij[(size_t)ch * 1280 + f];
  }
  __syncthreads();
  if (t < 160) {
    int c = t >> 4;
    float acc = 0.f;
    const float* up = uhat + ((size_t)b * 2048 + ch * 128) * 160 + t;
    if (it0) {
      const float cuni = 0.00048828125f;    // 1/2048 exact
#pragma unroll 4
      for (int rl = 0; rl < 128; ++rl) acc += cuni * up[(size_t)rl * 160];
    } else {
#pragma unroll 4
      for (int rl = 0; rl < 128; ++rl) acc += cl[rl * 10 + c] * up[(size_t)rl * 160];
    }
    sp[((size_t)b * 16 + ch) * 160 + t] = acc;
  }
}

__global__ __launch_bounds__(192)
void k_sjred(const float* __restrict__ sp, float* __restrict__ vj,
             float* __restrict__ dout, int finalit) {
  __shared__ float sl[160];
  __shared__ float fl[10];
  int b = blockIdx.x, t = threadIdx.x;
  if (t < 160) {
    float a = 0.f;
#pragma unroll
    for (int ch = 0; ch < 16; ++ch) a += sp[((size_t)b * 16 + ch) * 160 + t];
    sl[t] = a;
  }
  __syncthreads();
  if (t == 0) {
    float sv[10]; int rk[10];
    for (int c = 0; c < 10; ++c) sv[c] = sl[c * 16];
    for (int c = 0; c < 10; ++c) {
      int r = 0;
      for (int k = 0; k < 10; ++k)
        r += ((sv[k] < sv[c]) || (sv[k] == sv[c] && k < c)) ? 1 : 0;
      rk[c] = r;
    }
    int i1 = 0;
    for (int c = 0; c < 10; ++c) i1 += (sv[c] < DT1f) ? 1 : 0;
    float m1[10];
    for (int c = 0; c < 10; ++c) m1[c] = (rk[c] < i1 - 1) ? (DA1f * sv[c] + DB1f) : sv[c];
    int i2 = 0;
    for (int c = 0; c < 10; ++c) i2 += (m1[c] < 0.f) ? 1 : 0;
    float m2[10];
    for (int c = 0; c < 10; ++c)
      m2[c] = (rk[c] >= i1 && rk[c] < i2 - 1) ? (DA2f * m1[c] + DB2f) : m1[c];
    int i3 = 0;
    for (int c = 0; c < 10; ++c) i3 += (m2[c] < DT3f) ? 1 : 0;
    for (int c = 0; c < 10; ++c) {
      float m = (rk[c] >= i2 && rk[c] < i3 - 1) ? (DA3f * m2[c] + DB3f) : m2[c];
      m = (rk[c] >= i3 && rk[c] < 9) ? (DA4f * m + DB4f) : m;
      fl[c] = m;
    }
  }
  __syncthreads();
  if (t < 160) {
    int c = t >> 4, o = t & 15;
    float fv = fl[c];
    float v = fv * ((o == 0) ? fv : sl[t]);
    vj[(size_t)b * 160 + t] = v;
    if (finalit) dout[(size_t)b * 1184 + t] = v;
  }
}

// first=1: overwrite (replaces the k_zero init); else accumulate
__global__ __launch_bounds__(192)
void k_amean(const float* __restrict__ uhat, const float* __restrict__ vj,
             float* __restrict__ bij, int first) {
  __shared__ float vl[16000];
  int t = threadIdx.x, r0 = blockIdx.x * 8;
  for (int f = t; f < 16000; f += 192) vl[f] = vj[f];
  __syncthreads();
  if (t < 160) {
    int c = t >> 4;
    for (int rl = 0; rl < 8; ++rl) {
      int r = r0 + rl;
      float acc = 0.f;
      const float* up = uhat + (size_t)r * 160 + t;
#pragma unroll 4
      for (int b = 0; b < BATCH; ++b) acc += up[(size_t)b * 2048 * 160] * vl[b * 160 + t];
      for (int off = 8; off; off >>= 1) acc += __shfl_down(acc, off, 16);
      if ((t & 15) == 0) {
        float val = acc / 100.0f;
        bij[r * 10 + c] = first ? val : (bij[r * 10 + c] + val);
      }
    }
  }
}

__global__ __launch_bounds__(256)
void k_cls(const float* __restrict__ vj, int* __restrict__ idxg) {
  __shared__ float cl[1000];
  __shared__ float cm[10];
  __shared__ float cs[10];
  int t = threadIdx.x;
  for (int f = t; f < 1000; f += 256) {
    int b = f / 10, c = f - b * 10;
    float s = 0.f;
#pragma unroll
    for (int o = 0; o < 16; ++o) {
      float v = vj[(size_t)b * 160 + c * 16 + o];
      s += v * v;
    }
    cl[f] = sqrtf(s);
  }
  __syncthreads();
  if (t < 10) {
    float m = -3.402823466e38f;
    for (int b = 0; b < BATCH; ++b) m = fmaxf(m, cl[b * 10 + t]);
    float s = 0.f;
    for (int b = 0; b < BATCH; ++b) s += expf(cl[b * 10 + t] - m);
    cm[t] = m; cs[t] = s;
  }
  __syncthreads();
  for (int b = t; b < BATCH; b += 256) {
    float best = -1.f; int bi = 0;
    for (int c = 0; c < 10; ++c) {
      float val = expf(cl[b * 10 + c] - cm[c]) / cs[c];
      if (val > best) { best = val; bi = c; }
    }
    idxg[b] = bi;
  }
}

__global__ __launch_bounds__(256)
void k_dec1(const float* __restrict__ w1, const float* __restrict__ b1,
            const float* __restrict__ vj, const int* __restrict__ idxg,
            float* __restrict__ h1) {
  int b = blockIdx.x, t = threadIdx.x;
  int id = idxg[b];
  const float* v = vj + (size_t)b * 160 + id * 16;
  for (int j = t; j < 512; j += 256) {
    float acc = b1[j];
    const float* wr = w1 + (size_t)j * 160 + id * 16;
#pragma unroll
    for (int o = 0; o < 16; ++o) acc += wr[o] * v[o];
    h1[(size_t)b * 512 + j] = fmaxf(acc, 0.f);
  }
}

__global__ __launch_bounds__(256)
void k_dec2(const float* __restrict__ w2, const float* __restrict__ b2,
            const float* __restrict__ h1, float* __restrict__ h2) {
  __shared__ float red[4][64][4];
  int t = threadIdx.x, lane = t & 63, strip = t >> 6;
  int j = blockIdx.x * 64 + lane, bs = blockIdx.y * 4;
  float acc[4] = {0.f, 0.f, 0.f, 0.f};
  const float* wr = w2 + (size_t)j * 512 + strip * 128;
  const float* hb = h1 + (size_t)bs * 512 + strip * 128;
  for (int k4 = 0; k4 < 32; ++k4) {
    float4 wv = *(const float4*)(wr + k4 * 4);
    const float* h0 = hb + k4 * 4;
#pragma unroll
    for (int q = 0; q < 4; ++q) {
      float4 hv = *(const float4*)(h0 + q * 512);
      acc[q] += wv.x * hv.x + wv.y * hv.y + wv.z * hv.z + wv.w * hv.w;
    }
  }
#pragma unroll
  for (int q = 0; q < 4; ++q) red[strip][lane][q] = acc[q];
  __syncthreads();
  if (strip == 0) {
    float bias = b2[j];
#pragma unroll
    for (int q = 0; q < 4; ++q) {
      float tot = red[0][lane][q] + red[1][lane][q] + red[2][lane][q] + red[3][lane][q] + bias;
      h2[(size_t)(bs + q) * 1024 + j] = fmaxf(tot, 0.f);
    }
  }
}

__global__ __launch_bounds__(256)
void k_dec3(const float* __restrict__ w3, const float* __restrict__ b3,
            const float* __restrict__ h2, float* __restrict__ dout) {
  __shared__ float red[4][64][4];
  int t = threadIdx.x, lane = t & 63, strip = t >> 6;
  int j = blockIdx.x * 64 + lane, bs = blockIdx.y * 4;
  float acc[4] = {0.f, 0.f, 0.f, 0.f};
  const float* wr = w3 + (size_t)j * 1024 + strip * 256;
  const float* hb = h2 + (size_t)bs * 1024 + strip * 256;
  for (int k4 = 0; k4 < 64; ++k4) {
    float4 wv = *(const float4*)(wr + k4 * 4);
    const float* h0 = hb + k4 * 4;
#pragma unroll
    for (int q = 0; q < 4; ++q) {
      float4 hv = *(const float4*)(h0 + q * 1024);
      acc[q] += wv.x * hv.x + wv.y * hv.y + wv.z * hv.z + wv.w * hv.w;
    }
  }
#pragma unroll
  for (int q = 0; q < 4; ++q) red[strip][lane][q] = acc[q];
  __syncthreads();
  if (strip == 0) {
    float bias = b3[j];
#pragma unroll
    for (int q = 0; q < 4; ++q) {
      float tot = red[0][lane][q] + red[1][lane][q] + red[2][lane][q] + red[3][lane][q] + bias;
      dout[(size_t)(bs + q) * 1184 + 160 + j] = 1.f / (1.f + expf(-tot));
    }
  }
}

// ---------------------------------------------------------------------------
extern "C" void kernel_launch(void* const* d_in, const int* in_sizes, int n_in,
                              void* d_out, int out_size, void* d_ws, size_t ws_size,
                              hipStream_t stream) {
  (void)in_sizes; (void)n_in; (void)out_size; (void)ws_size;
  const float* data = (const float*)d_in[0];
  const float* c1w  = (const float*)d_in[1];
  const float* c1b  = (const float*)d_in[2];
  const float* pw   = (const float*)d_in[3];
  const float* pb   = (const float*)d_in[4];
  const float* Wdc  = (const float*)d_in[5];
  const float* w1   = (const float*)d_in[6];
  const float* b1   = (const float*)d_in[7];
  const float* w2   = (const float*)d_in[8];
  const float* b2   = (const float*)d_in[9];
  const float* w3   = (const float*)d_in[10];
  const float* b3   = (const float*)d_in[11];
  float* out = (float*)d_out;
  float* ws  = (float*)d_ws;

  float* WT   = ws + OFF_WT;
  float* X1   = ws + OFF_X1;
  float* PU   = ws + OFF_PU;
  float* UHAT = ws + OFF_UHAT;
  float* U    = ws + OFF_U;
  float* BIJ  = ws + OFF_BIJ;
  float* CIJ  = ws + OFF_CIJ;
  float* SP   = ws + OFF_SP;
  float* VJ   = ws + OFF_VJ;
  int*   IDX  = (int*)(ws + OFF_IDX);
  float* H1   = ws + OFF_H1;
  float* H2   = ws + OFF_H2;

  k_transpose_w<<<dim3(256, 4), 256, 0, stream>>>(pw, WT);
  k_conv1<<<dim3(BATCH, 8), 256, 0, stream>>>(data, c1w, c1b, X1);
  k_prim<<<dim3(8, 8, 25), 256, 0, stream>>>(X1, WT, PU);
  k_ured<<<1600, 256, 0, stream>>>(PU, pb, U);
  k_squash<<<BATCH, 256, 0, stream>>>(U);                     // U -> u_sq in place
  k_uhat<<<256, 192, 0, stream>>>(Wdc, U, UHAT);              // clobbers WT/X1/PU (dead)

  for (int it = 0; it < 3; ++it) {
    if (it > 0) k_softc<<<10, 256, 0, stream>>>(BIJ, CIJ);
    k_sjpart<<<dim3(BATCH, 16), 192, 0, stream>>>(CIJ, UHAT, SP, it == 0 ? 1 : 0);
    k_sjred<<<BATCH, 192, 0, stream>>>(SP, VJ, out, it == 2 ? 1 : 0);
    if (it < 2) k_amean<<<256, 192, 0, stream>>>(UHAT, VJ, BIJ, it == 0 ? 1 : 0);
  }

  k_cls<<<1, 256, 0, stream>>>(VJ, IDX);
  k_dec1<<<BATCH, 256, 0, stream>>>(w1, b1, VJ, IDX, H1);
  k_dec2<<<dim3(16, 25), 256, 0, stream>>>(w2, b2, H1, H2);
  k_dec3<<<dim3(16, 25), 256, 0, stream>>>(w3, b3, H2, out);
}

// Round 7
// 1290.124 us; speedup vs baseline: 1.3134x; 1.1314x over previous
//
#include <hip/hip_runtime.h>
#include <cstdint>
#include <cstddef>

// ---------------------------------------------------------------------------
// CapsNet forward, f32 end-to-end (precision-critical: the sort-based squash
// flips discrete segments on ~1e-7 perturbations of s_j, so no bf16 on that
// path).
//
// Workspace phases (floats), peak footprint 33.2M fl:
//   A (prim):    WT[0..5.31M] X1[5.31..20.05M] PU[20.05..33.16M]
//   B (ured):    U[33.16..34.80M]
//   C (uhat):    UHAT[0..32.77M] + U
//   D (routing): UHAT + smalls[32.77M..33.23M]
// ---------------------------------------------------------------------------

#define BATCH 100

static const size_t OFF_WT   = 0;            // 256*81*256 = 5,308,416   (dead after prim)
static const size_t OFF_X1   = 5308416;      // 100*256*576 = 14,745,600 (dead after prim)
static const size_t OFF_PU   = 20054016;     // 8*100*2048*8 = 13,107,200 (dead after k_ured)
static const size_t OFF_UHAT = 0;            // 100*2048*160 = 32,768,000
static const size_t OFF_U    = 33161216;     // 100*2048*8 = 1,638,400 (dead after k_uhat)
static const size_t OFF_BIJ  = 32768000;     // 2048*10
static const size_t OFF_CIJ  = 32788480;     // 2048*10
static const size_t OFF_SP   = 32808960;     // 100*16*160 = 256,000
static const size_t OFF_VJ   = 33064960;     // 100*160
static const size_t OFF_IDX  = 33080960;     // 100 ints (128 slots)
static const size_t OFF_H1   = 33081088;     // 100*512
static const size_t OFF_H2   = 33132288;     // 100*1024 -> end 33,234,688

// piecewise-affine squash constants
#define PT1f -13.46416092f
#define PA1f 0.000242759f
#define PB1f 0.024488359f
#define PA2f 0.002769205f
#define PB2f 0.06089699f
#define PT3f 13.23405266f
#define PA3f -0.002828244f
#define PB3f 0.061313814f
#define PA4f -0.000219038f
#define PB4f 0.023874787f

#define DT1f -0.075410217f
#define DA1f -0.074520095f
#define DB1f 0.349297946f
#define DA2f -0.534473989f
#define DB2f 0.27196494f
#define DT3f 0.062207676f
#define DA3f 0.637642944f
#define DB3f 0.295330779f
#define DA4f 0.169344703f
#define DB4f 0.353784456f

// x-row LDS placement for k_prim: STRICTLY INCREASING (injective) swizzle.
//   rowstart(r) = 12*r + 4*(r>>1)   (steps +12/+16 -> no collisions)
// Quad signature S(r) = (3r + (r>>1)) mod 8; rows read together differ by 2:
// S steps by 7 (coprime 8) -> 8 distinct bank-quads per read instr.
#define XROW(r) ((r) * 12 + ((r) >> 1) * 4)
#define XPH 332          // phase stride (rowstart(23)=320 + 12)
#define XTB 664          // per-tb stride (2 phases)

// ---------------------------------------------------------------------------
// w_t[(ci*81+tap)*256 + co]  <-  prim_w[co][ci][tap]
// ---------------------------------------------------------------------------
__global__ __launch_bounds__(256)
void k_transpose_w(const float* __restrict__ w, float* __restrict__ wt) {
  __shared__ float tile[64 * 82];
  int ci = blockIdx.x, co0 = blockIdx.y * 64, t = threadIdx.x;
  for (int f = t; f < 64 * 81; f += 256) {
    int col = f / 81, tap = f - col * 81;
    tile[col * 82 + tap] = w[(size_t)(co0 + col) * 20736 + (size_t)ci * 81 + tap];
  }
  __syncthreads();
  for (int g = t; g < 64 * 81; g += 256) {
    int tap = g / 64, col = g - tap * 64;
    wt[((size_t)ci * 81 + tap) * 256 + co0 + col] = tile[col * 82 + tap];
  }
}

// ---------------------------------------------------------------------------
// conv1 + bias + relu: data(100,1,32,32) -> x1(100,256,24,24)
// ---------------------------------------------------------------------------
__global__ __launch_bounds__(256)
void k_conv1(const float* __restrict__ data, const float* __restrict__ cw,
             const float* __restrict__ cb, float* __restrict__ x1) {
  __shared__ float img[1024];
  __shared__ float wl[81 * 32];     // [tap][c]
  int b = blockIdx.x, cg = blockIdx.y, t = threadIdx.x;
  for (int f = t; f < 1024; f += 256) img[f] = data[(size_t)b * 1024 + f];
  for (int f = t; f < 2592; f += 256) {
    int tap = f >> 5, c = f & 31;
    wl[f] = cw[(size_t)(cg * 32 + c) * 81 + tap];
  }
  __syncthreads();
  for (int task = t; task < 1152; task += 256) {
    int q = task % 144, cq = task / 144;
    int p0 = q * 4, oh = p0 / 24, ow0 = p0 % 24;
    float a[4][4];
#pragma unroll
    for (int i = 0; i < 4; ++i)
#pragma unroll
      for (int j = 0; j < 4; ++j) a[i][j] = 0.f;
    for (int kh = 0; kh < 9; ++kh) {
      const float* ir = &img[(oh + kh) * 32 + ow0];
      const float* wr = &wl[kh * 9 * 32 + cq * 4];
#pragma unroll
      for (int kw = 0; kw < 9; ++kw) {
        float4 wv = *(const float4*)(wr + kw * 32);
#pragma unroll
        for (int j = 0; j < 4; ++j) {
          float xv = ir[kw + j];
          a[0][j] = fmaf(wv.x, xv, a[0][j]);
          a[1][j] = fmaf(wv.y, xv, a[1][j]);
          a[2][j] = fmaf(wv.z, xv, a[2][j]);
          a[3][j] = fmaf(wv.w, xv, a[3][j]);
        }
      }
    }
#pragma unroll
    for (int cc = 0; cc < 4; ++cc) {
      int c = cg * 32 + cq * 4 + cc;
      float bias = cb[c];
      float4 o4 = make_float4(fmaxf(a[cc][0] + bias, 0.f), fmaxf(a[cc][1] + bias, 0.f),
                              fmaxf(a[cc][2] + bias, 0.f), fmaxf(a[cc][3] + bias, 0.f));
      *(float4*)&x1[((size_t)(b * 256 + c) * 24 + oh) * 24 + ow0] = o4;
    }
  }
}

// ---------------------------------------------------------------------------
// prim conv v7: x1(100,256,24,24) -> PU[split](100,2048,8), 9x9 stride 2.
// Block = 256 thr = 4 batches x (8 coq x 8 oh); thread tile 4co x 8ow.
// 32 ci per block (8-way ci split).
// x phase-split (even/odd cols) with INJECTIVE bank swizzle XROW(r):
//   inner-read bank-quads (7*oh + const) mod 8 -> all 8 distinct ->
//   conflict-free; staging stores worst-case 2-way (free).
// LDS = 10368(w) + 10624(x) = 20992 B -> 7 blocks/CU.
// Per-output FMA order identical to v5 -> bitwise-same partials.
// ---------------------------------------------------------------------------
__global__ __launch_bounds__(256, 8)
void k_prim(const float* __restrict__ x1, const float* __restrict__ wt,
            float* __restrict__ pu) {
  __shared__ float wsh[81 * 32];        // [tap][co32]                 10368 B
  __shared__ float xsh[4 * XTB];        // [tb][phase][swizzled rows]  10624 B
  int t = threadIdx.x;
  int tb = t >> 6, tl = t & 63;
  int coq = tl >> 3, oh = tl & 7;
  int ci_base = blockIdx.x * 32, cog = blockIdx.y, bq = blockIdx.z;
  int b = bq * 4 + tb;

  float acc[4][8];
#pragma unroll
  for (int i = 0; i < 4; ++i)
#pragma unroll
    for (int j = 0; j < 8; ++j) acc[i][j] = 0.f;

#pragma unroll 1
  for (int ci = ci_base; ci < ci_base + 32; ++ci) {
    __syncthreads();
    // stage x: 288 jobs (4 tb x 24 rows x 3 col-octs); each job packs 8 cols
    // into 1 even float4 + 1 odd float4 at swizzled row offsets.
    for (int f = t; f < 288; f += 256) {
      int tbj = f / 72, rem = f - tbj * 72;
      int r = rem / 3, oct = rem - r * 3;
      const float* gp = &x1[((size_t)(bq * 4 + tbj) * 256 + ci) * 576 + r * 24 + oct * 8];
      float4 v1 = *(const float4*)gp;
      float4 v2 = *(const float4*)(gp + 4);
      float* eb = &xsh[tbj * XTB + XROW(r) + oct * 4];
      *(float4*)eb = make_float4(v1.x, v1.z, v2.x, v2.z);          // even cols
      *(float4*)(eb + XPH) = make_float4(v1.y, v1.w, v2.y, v2.w);  // odd cols
    }
    // stage w: 648 float4 jobs (81 tap x 8 colq) — dense b128 stores
    for (int f = t; f < 648; f += 256) {
      int tap = f >> 3, cq = f & 7;
      float4 v = *(const float4*)&wt[((size_t)ci * 81 + tap) * 256 + cog * 32 + cq * 4];
      *(float4*)&wsh[tap * 32 + cq * 4] = v;
    }
    __syncthreads();
    const float* xb = &xsh[tb * XTB];
    const float* wb = &wsh[coq * 4];
#pragma unroll 3
    for (int kh = 0; kh < 9; ++kh) {
      int r = 2 * oh + kh;
      const float* xe = xb + XROW(r);
      float ew[12], ov[12];
      *(float4*)&ew[0] = *(const float4*)xe;
      *(float4*)&ew[4] = *(const float4*)(xe + 4);
      *(float4*)&ew[8] = *(const float4*)(xe + 8);
      *(float4*)&ov[0] = *(const float4*)(xe + XPH);
      *(float4*)&ov[4] = *(const float4*)(xe + XPH + 4);
      *(float4*)&ov[8] = *(const float4*)(xe + XPH + 8);
      const float* wr = wb + kh * 9 * 32;
#pragma unroll
      for (int p = 0; p < 5; ++p) {                 // kw = 2p (even cols)
        float4 wv = *(const float4*)(wr + p * 64);
#pragma unroll
        for (int j = 0; j < 8; ++j) {
          float xv = ew[p + j];
          acc[0][j] = fmaf(wv.x, xv, acc[0][j]);
          acc[1][j] = fmaf(wv.y, xv, acc[1][j]);
          acc[2][j] = fmaf(wv.z, xv, acc[2][j]);
          acc[3][j] = fmaf(wv.w, xv, acc[3][j]);
        }
      }
#pragma unroll
      for (int p = 0; p < 4; ++p) {                 // kw = 2p+1 (odd cols)
        float4 wv = *(const float4*)(wr + 32 + p * 64);
#pragma unroll
        for (int j = 0; j < 8; ++j) {
          float xv = ov[p + j];
          acc[0][j] = fmaf(wv.x, xv, acc[0][j]);
          acc[1][j] = fmaf(wv.y, xv, acc[1][j]);
          acc[2][j] = fmaf(wv.z, xv, acc[2][j]);
          acc[3][j] = fmaf(wv.w, xv, acc[3][j]);
        }
      }
    }
  }
  // partial write (no bias; k_ured adds it): pu[split][b][r=co*8+oh][ow]
  float* pp = pu + (((size_t)blockIdx.x * BATCH + b) * 2048 +
                    (cog * 32 + coq * 4) * 8 + oh) * 8;
#pragma unroll
  for (int cc = 0; cc < 4; ++cc) {
    *(float4*)(pp + cc * 64)     = make_float4(acc[cc][0], acc[cc][1], acc[cc][2], acc[cc][3]);
    *(float4*)(pp + cc * 64 + 4) = make_float4(acc[cc][4], acc[cc][5], acc[cc][6], acc[cc][7]);
  }
}

// u = sum of 8 partials (ci-ascending order) + bias
__global__ __launch_bounds__(256)
void k_ured(const float* __restrict__ pu, const float* __restrict__ pb,
            float* __restrict__ u) {
  int g4 = blockIdx.x * 256 + threadIdx.x;     // 409,600 float4s
  if (g4 >= 409600) return;
  size_t g = (size_t)g4 * 4;
  const size_t S = 1638400;
  float4 s = *(const float4*)(pu + g);
#pragma unroll
  for (int k = 1; k < 8; ++k) {
    float4 p = *(const float4*)(pu + (size_t)k * S + g);
    s.x += p.x; s.y += p.y; s.z += p.z; s.w += p.w;
  }
  int r = (int)((g >> 3) & 2047);
  float bias = pb[r >> 3];
  float4 o = make_float4(s.x + bias, s.y + bias, s.z + bias, s.w + bias);
  *(float4*)(u + g) = o;
}

// ---------------------------------------------------------------------------
// primary squash: stable bitonic sort per batch row + exact where-chain,
// then u_sq = mag * u in place.
// ---------------------------------------------------------------------------
__global__ __launch_bounds__(256)
void k_squash(float* __restrict__ u) {
  __shared__ float kv[2048];
  __shared__ int kid[2048];
  __shared__ int red[256];
  int b = blockIdx.x, t = threadIdx.x;
  for (int r = t; r < 2048; r += 256) {
    kv[r] = u[((size_t)b * 2048 + r) * 8];
    kid[r] = r;
  }
  __syncthreads();
  for (int size = 2; size <= 2048; size <<= 1) {
    for (int stride = size >> 1; stride > 0; stride >>= 1) {
#pragma unroll 1
      for (int s = 0; s < 4; ++s) {
        int i = t + s * 256;
        int pos = 2 * i - (i & (stride - 1));
        int q = pos + stride;
        float va = kv[pos], vb = kv[q];
        int ia = kid[pos], ib = kid[q];
        bool gt = (va > vb) || (va == vb && ia > ib);
        bool up = ((pos & size) == 0);
        if (gt == up) { kv[pos] = vb; kv[q] = va; kid[pos] = ib; kid[q] = ia; }
      }
      __syncthreads();
    }
  }
  int loc = 0;
#pragma unroll
  for (int s = 0; s < 8; ++s) loc += (kv[t + s * 256] < PT1f) ? 1 : 0;
  red[t] = loc; __syncthreads();
  for (int off = 128; off; off >>= 1) { if (t < off) red[t] += red[t + off]; __syncthreads(); }
  int i1 = red[0]; __syncthreads();
  float m1v[8];
  loc = 0;
#pragma unroll
  for (int s = 0; s < 8; ++s) {
    int p = t + s * 256;
    float v = kv[p];
    float m = (p < i1 - 1) ? (PA1f * v + PB1f) : v;
    m1v[s] = m;
    loc += (m < 0.f) ? 1 : 0;
  }
  red[t] = loc; __syncthreads();
  for (int off = 128; off; off >>= 1) { if (t < off) red[t] += red[t + off]; __syncthreads(); }
  int i2 = red[0]; __syncthreads();
  float m2v[8];
  loc = 0;
#pragma unroll
  for (int s = 0; s < 8; ++s) {
    int p = t + s * 256;
    float m = (p >= i1 && p < i2 - 1) ? (PA2f * m1v[s] + PB2f) : m1v[s];
    m2v[s] = m;
    loc += (m < PT3f) ? 1 : 0;
  }
  red[t] = loc; __syncthreads();
  for (int off = 128; off; off >>= 1) { if (t < off) red[t] += red[t + off]; __syncthreads(); }
  int i3 = red[0]; __syncthreads();
#pragma unroll
  for (int s = 0; s < 8; ++s) {
    int p = t + s * 256;
    float m = m2v[s];
    m = (p >= i2 && p < i3 - 1) ? (PA3f * m + PB3f) : m;
    m = (p >= i3 && p < 2047) ? (PA4f * m + PB4f) : m;
    int rid = kid[p];
    float* row = u + ((size_t)b * 2048 + rid) * 8;
    float4 lo = *(float4*)row;
    float4 hi = *(float4*)(row + 4);
    lo.x *= m; lo.y *= m; lo.z *= m; lo.w *= m;
    hi.x *= m; hi.y *= m; hi.z *= m; hi.w *= m;
    *(float4*)row = lo;
    *(float4*)(row + 4) = hi;
  }
}

// ---------------------------------------------------------------------------
// u_hat[b][r][c*16+o] = sum_i W_dc[r][c][o][i] * u_sq[b][r][i]
// 4-row chunks -> per-b writes are 2560 B contiguous
// ---------------------------------------------------------------------------
__global__ __launch_bounds__(192)
void k_uhat(const float* __restrict__ Wdc, const float* __restrict__ usq,
            float* __restrict__ uhat) {
  int t = threadIdx.x;
  if (t >= 160) return;
  int r0 = blockIdx.x * 8;
#pragma unroll 1
  for (int half = 0; half < 2; ++half) {
    int rb = r0 + half * 4;
    float4 wa[4], wb4[4];
#pragma unroll
    for (int rl = 0; rl < 4; ++rl) {
      const float* wp = Wdc + ((size_t)(rb + rl) * 160 + t) * 8;
      wa[rl]  = *(const float4*)wp;
      wb4[rl] = *(const float4*)(wp + 4);
    }
#pragma unroll 2
    for (int b = 0; b < BATCH; ++b) {
      const float* ub = usq + ((size_t)b * 2048 + rb) * 8;   // 32 consecutive fl
      float* op = uhat + ((size_t)b * 2048 + rb) * 160 + t;
#pragma unroll
      for (int rl = 0; rl < 4; ++rl) {
        const float* us = ub + rl * 8;
        float v = us[0] * wa[rl].x + us[1] * wa[rl].y + us[2] * wa[rl].z + us[3] * wa[rl].w +
                  us[4] * wb4[rl].x + us[5] * wb4[rl].y + us[6] * wb4[rl].z + us[7] * wb4[rl].w;
        op[(size_t)rl * 160] = v;
      }
    }
  }
}

__global__ __launch_bounds__(256)
void k_softc(const float* __restrict__ bij, float* __restrict__ cij) {
  __shared__ float red[256];
  int c = blockIdx.x, t = threadIdx.x;
  float m = -3.402823466e38f;
  for (int r = t; r < 2048; r += 256) m = fmaxf(m, bij[r * 10 + c]);
  red[t] = m; __syncthreads();
  for (int off = 128; off; off >>= 1) { if (t < off) red[t] = fmaxf(red[t], red[t + off]); __syncthreads(); }
  m = red[0]; __syncthreads();
  float s = 0.f;
  for (int r = t; r < 2048; r += 256) s += expf(bij[r * 10 + c] - m);
  red[t] = s; __syncthreads();
  for (int off = 128; off; off >>= 1) { if (t < off) red[t] += red[t + off]; __syncthreads(); }
  s = red[0];
  for (int r = t; r < 2048; r += 256) cij[r * 10 + c] = expf(bij[r * 10 + c] - m) / s;
}

// it0: c_ij = softmax(zeros) = 1/2048 exactly -> uniform constant, no CIJ read
__global__ __launch_bounds__(192)
void k_sjpart(const float* __restrict__ cij, const float* __restrict__ uhat,
              float* __restrict__ sp, int it0) {
  __shared__ float cl[1280];
  int b = blockIdx.x, ch = blockIdx.y, t = threadIdx.x;
  if (!it0) {
    for (int f = t; f < 1280; f += 192) cl[f] = cij[(size_t)ch * 1280 + f];
  }
  __syncthreads();
  if (t < 160) {
    int c = t >> 4;
    float acc = 0.f;
    const float* up = uhat + ((size_t)b * 2048 + ch * 128) * 160 + t;
    if (it0) {
      const float cuni = 0.00048828125f;    // 1/2048 exact
#pragma unroll 4
      for (int rl = 0; rl < 128; ++rl) acc += cuni * up[(size_t)rl * 160];
    } else {
#pragma unroll 4
      for (int rl = 0; rl < 128; ++rl) acc += cl[rl * 10 + c] * up[(size_t)rl * 160];
    }
    sp[((size_t)b * 16 + ch) * 160 + t] = acc;
  }
}

__global__ __launch_bounds__(192)
void k_sjred(const float* __restrict__ sp, float* __restrict__ vj,
             float* __restrict__ dout, int finalit) {
  __shared__ float sl[160];
  __shared__ float fl[10];
  int b = blockIdx.x, t = threadIdx.x;
  if (t < 160) {
    float a = 0.f;
#pragma unroll
    for (int ch = 0; ch < 16; ++ch) a += sp[((size_t)b * 16 + ch) * 160 + t];
    sl[t] = a;
  }
  __syncthreads();
  if (t == 0) {
    float sv[10]; int rk[10];
    for (int c = 0; c < 10; ++c) sv[c] = sl[c * 16];
    for (int c = 0; c < 10; ++c) {
      int r = 0;
      for (int k = 0; k < 10; ++k)
        r += ((sv[k] < sv[c]) || (sv[k] == sv[c] && k < c)) ? 1 : 0;
      rk[c] = r;
    }
    int i1 = 0;
    for (int c = 0; c < 10; ++c) i1 += (sv[c] < DT1f) ? 1 : 0;
    float m1[10];
    for (int c = 0; c < 10; ++c) m1[c] = (rk[c] < i1 - 1) ? (DA1f * sv[c] + DB1f) : sv[c];
    int i2 = 0;
    for (int c = 0; c < 10; ++c) i2 += (m1[c] < 0.f) ? 1 : 0;
    float m2[10];
    for (int c = 0; c < 10; ++c)
      m2[c] = (rk[c] >= i1 && rk[c] < i2 - 1) ? (DA2f * m1[c] + DB2f) : m1[c];
    int i3 = 0;
    for (int c = 0; c < 10; ++c) i3 += (m2[c] < DT3f) ? 1 : 0;
    for (int c = 0; c < 10; ++c) {
      float m = (rk[c] >= i2 && rk[c] < i3 - 1) ? (DA3f * m2[c] + DB3f) : m2[c];
      m = (rk[c] >= i3 && rk[c] < 9) ? (DA4f * m + DB4f) : m;
      fl[c] = m;
    }
  }
  __syncthreads();
  if (t < 160) {
    int c = t >> 4, o = t & 15;
    float fv = fl[c];
    float v = fv * ((o == 0) ? fv : sl[t]);
    vj[(size_t)b * 160 + t] = v;
    if (finalit) dout[(size_t)b * 1184 + t] = v;
  }
}

// b-outer / r-inner -> per-b reads are 5120 B contiguous. Accumulation order
// per (r,t) unchanged (b-sequential, then o-shuffle).
__global__ __launch_bounds__(192)
void k_amean(const float* __restrict__ uhat, const float* __restrict__ vj,
             float* __restrict__ bij, int first) {
  __shared__ float vl[16000];
  int t = threadIdx.x, r0 = blockIdx.x * 8;
  for (int f = t; f < 16000; f += 192) vl[f] = vj[f];
  __syncthreads();
  if (t < 160) {
    int c = t >> 4;
    float acc[8];
#pragma unroll
    for (int rl = 0; rl < 8; ++rl) acc[rl] = 0.f;
    const float* up0 = uhat + (size_t)r0 * 160 + t;
#pragma unroll 2
    for (int b = 0; b < BATCH; ++b) {
      float vv = vl[b * 160 + t];
      const float* up = up0 + (size_t)b * 327680;
#pragma unroll
      for (int rl = 0; rl < 8; ++rl)
        acc[rl] = fmaf(up[(size_t)rl * 160], vv, acc[rl]);
    }
#pragma unroll
    for (int rl = 0; rl < 8; ++rl) {
      float a = acc[rl];
      for (int off = 8; off; off >>= 1) a += __shfl_down(a, off, 16);
      if ((t & 15) == 0) {
        int r = r0 + rl;
        float val = a / 100.0f;
        bij[r * 10 + c] = first ? val : (bij[r * 10 + c] + val);
      }
    }
  }
}

__global__ __launch_bounds__(256)
void k_cls(const float* __restrict__ vj, int* __restrict__ idxg) {
  __shared__ float cl[1000];
  __shared__ float cm[10];
  __shared__ float cs[10];
  int t = threadIdx.x;
  for (int f = t; f < 1000; f += 256) {
    int b = f / 10, c = f - b * 10;
    float s = 0.f;
#pragma unroll
    for (int o = 0; o < 16; ++o) {
      float v = vj[(size_t)b * 160 + c * 16 + o];
      s += v * v;
    }
    cl[f] = sqrtf(s);
  }
  __syncthreads();
  if (t < 10) {
    float m = -3.402823466e38f;
    for (int b = 0; b < BATCH; ++b) m = fmaxf(m, cl[b * 10 + t]);
    float s = 0.f;
    for (int b = 0; b < BATCH; ++b) s += expf(cl[b * 10 + t] - m);
    cm[t] = m; cs[t] = s;
  }
  __syncthreads();
  for (int b = t; b < BATCH; b += 256) {
    float best = -1.f; int bi = 0;
    for (int c = 0; c < 10; ++c) {
      float val = expf(cl[b * 10 + c] - cm[c]) / cs[c];
      if (val > best) { best = val; bi = c; }
    }
    idxg[b] = bi;
  }
}

__global__ __launch_bounds__(256)
void k_dec1(const float* __restrict__ w1, const float* __restrict__ b1,
            const float* __restrict__ vj, const int* __restrict__ idxg,
            float* __restrict__ h1) {
  int b = blockIdx.x, t = threadIdx.x;
  int id = idxg[b];
  const float* v = vj + (size_t)b * 160 + id * 16;
  for (int j = t; j < 512; j += 256) {
    float acc = b1[j];
    const float* wr = w1 + (size_t)j * 160 + id * 16;
#pragma unroll
    for (int o = 0; o < 16; ++o) acc += wr[o] * v[o];
    h1[(size_t)b * 512 + j] = fmaxf(acc, 0.f);
  }
}

__global__ __launch_bounds__(256)
void k_dec2(const float* __restrict__ w2, const float* __restrict__ b2,
            const float* __restrict__ h1, float* __restrict__ h2) {
  __shared__ float red[4][64][4];
  int t = threadIdx.x, lane = t & 63, strip = t >> 6;
  int j = blockIdx.x * 64 + lane, bs = blockIdx.y * 4;
  float acc[4] = {0.f, 0.f, 0.f, 0.f};
  const float* wr = w2 + (size_t)j * 512 + strip * 128;
  const float* hb = h1 + (size_t)bs * 512 + strip * 128;
  for (int k4 = 0; k4 < 32; ++k4) {
    float4 wv = *(const float4*)(wr + k4 * 4);
    const float* h0 = hb + k4 * 4;
#pragma unroll
    for (int q = 0; q < 4; ++q) {
      float4 hv = *(const float4*)(h0 + q * 512);
      acc[q] += wv.x * hv.x + wv.y * hv.y + wv.z * hv.z + wv.w * hv.w;
    }
  }
#pragma unroll
  for (int q = 0; q < 4; ++q) red[strip][lane][q] = acc[q];
  __syncthreads();
  if (strip == 0) {
    float bias = b2[j];
#pragma unroll
    for (int q = 0; q < 4; ++q) {
      float tot = red[0][lane][q] + red[1][lane][q] + red[2][lane][q] + red[3][lane][q] + bias;
      h2[(size_t)(bs + q) * 1024 + j] = fmaxf(tot, 0.f);
    }
  }
}

__global__ __launch_bounds__(256)
void k_dec3(const float* __restrict__ w3, const float* __restrict__ b3,
            const float* __restrict__ h2, float* __restrict__ dout) {
  __shared__ float red[4][64][4];
  int t = threadIdx.x, lane = t & 63, strip = t >> 6;
  int j = blockIdx.x * 64 + lane, bs = blockIdx.y * 4;
  float acc[4] = {0.f, 0.f, 0.f, 0.f};
  const float* wr = w3 + (size_t)j * 1024 + strip * 256;
  const float* hb = h2 + (size_t)bs * 1024 + strip * 256;
  for (int k4 = 0; k4 < 64; ++k4) {
    float4 wv = *(const float4*)(wr + k4 * 4);
    const float* h0 = hb + k4 * 4;
#pragma unroll
    for (int q = 0; q < 4; ++q) {
      float4 hv = *(const float4*)(h0 + q * 1024);
      acc[q] += wv.x * hv.x + wv.y * hv.y + wv.z * hv.z + wv.w * hv.w;
    }
  }
#pragma unroll
  for (int q = 0; q < 4; ++q) red[strip][lane][q] = acc[q];
  __syncthreads();
  if (strip == 0) {
    float bias = b3[j];
#pragma unroll
    for (int q = 0; q < 4; ++q) {
      float tot = red[0][lane][q] + red[1][lane][q] + red[2][lane][q] + red[3][lane][q] + bias;
      dout[(size_t)(bs + q) * 1184 + 160 + j] = 1.f / (1.f + expf(-tot));
    }
  }
}

// ---------------------------------------------------------------------------
extern "C" void kernel_launch(void* const* d_in, const int* in_sizes, int n_in,
                              void* d_out, int out_size, void* d_ws, size_t ws_size,
                              hipStream_t stream) {
  (void)in_sizes; (void)n_in; (void)out_size; (void)ws_size;
  const float* data = (const float*)d_in[0];
  const float* c1w  = (const float*)d_in[1];
  const float* c1b  = (const float*)d_in[2];
  const float* pw   = (const float*)d_in[3];
  const float* pb   = (const float*)d_in[4];
  const float* Wdc  = (const float*)d_in[5];
  const float* w1   = (const float*)d_in[6];
  const float* b1   = (const float*)d_in[7];
  const float* w2   = (const float*)d_in[8];
  const float* b2   = (const float*)d_in[9];
  const float* w3   = (const float*)d_in[10];
  const float* b3   = (const float*)d_in[11];
  float* out = (float*)d_out;
  float* ws  = (float*)d_ws;

  float* WT   = ws + OFF_WT;
  float* X1   = ws + OFF_X1;
  float* PU   = ws + OFF_PU;
  float* UHAT = ws + OFF_UHAT;
  float* U    = ws + OFF_U;
  float* BIJ  = ws + OFF_BIJ;
  float* CIJ  = ws + OFF_CIJ;
  float* SP   = ws + OFF_SP;
  float* VJ   = ws + OFF_VJ;
  int*   IDX  = (int*)(ws + OFF_IDX);
  float* H1   = ws + OFF_H1;
  float* H2   = ws + OFF_H2;

  k_transpose_w<<<dim3(256, 4), 256, 0, stream>>>(pw, WT);
  k_conv1<<<dim3(BATCH, 8), 256, 0, stream>>>(data, c1w, c1b, X1);
  k_prim<<<dim3(8, 8, 25), 256, 0, stream>>>(X1, WT, PU);
  k_ured<<<1600, 256, 0, stream>>>(PU, pb, U);
  k_squash<<<BATCH, 256, 0, stream>>>(U);                     // U -> u_sq in place
  k_uhat<<<256, 192, 0, stream>>>(Wdc, U, UHAT);              // clobbers WT/X1/PU (dead)

  for (int it = 0; it < 3; ++it) {
    if (it > 0) k_softc<<<10, 256, 0, stream>>>(BIJ, CIJ);
    k_sjpart<<<dim3(BATCH, 16), 192, 0, stream>>>(CIJ, UHAT, SP, it == 0 ? 1 : 0);
    k_sjred<<<BATCH, 192, 0, stream>>>(SP, VJ, out, it == 2 ? 1 : 0);
    if (it < 2) k_amean<<<256, 192, 0, stream>>>(UHAT, VJ, BIJ, it == 0 ? 1 : 0);
  }

  k_cls<<<1, 256, 0, stream>>>(VJ, IDX);
  k_dec1<<<BATCH, 256, 0, stream>>>(w1, b1, VJ, IDX, H1);
  k_dec2<<<dim3(16, 25), 256, 0, stream>>>(w2, b2, H1, H2);
  k_dec3<<<dim3(16, 25), 256, 0, stream>>>(w3, b3, H2, out);
}